// Round 2
// baseline (1654.243 us; speedup 1.0000x reference)
//
#include <hip/hip_runtime.h>
#include <hip/hip_bf16.h>

#define HD __device__ __forceinline__

static constexpr int H = 128;
static constexpr int G = 100;
static constexpr int L = 4;
static constexpr int C = 10;

// ---------------- CSR build ----------------
__global__ void count_kernel(const int* __restrict__ dst, int E, int* __restrict__ indptr) {
    int e = blockIdx.x * blockDim.x + threadIdx.x;
    if (e < E) atomicAdd(&indptr[1 + dst[e]], 1);
}

__global__ void scan_kernel(int* __restrict__ indptr, int* __restrict__ cursor, int N) {
    __shared__ int ls[1024];
    int t = threadIdx.x;
    int chunk = (N + 1023) >> 10;
    int b = t * chunk;
    int e = min(b + chunk, N);
    int s = 0;
    for (int i = b; i < e; ++i) s += indptr[1 + i];
    ls[t] = s;
    __syncthreads();
    for (int off = 1; off < 1024; off <<= 1) {
        int v = (t >= off) ? ls[t - off] : 0;
        __syncthreads();
        ls[t] += v;
        __syncthreads();
    }
    int prefix = (t == 0) ? 0 : ls[t - 1];
    for (int i = b; i < e; ++i) { prefix += indptr[1 + i]; indptr[1 + i] = prefix; }
    __syncthreads();
    for (int i = t; i < N; i += 1024) cursor[i] = indptr[i];
}

__global__ void fill_kernel(const int* __restrict__ src, const int* __restrict__ dst, int E,
                            int* __restrict__ cursor, int* __restrict__ esrc) {
    int e = blockIdx.x * blockDim.x + threadIdx.x;
    if (e < E) {
        int pos = atomicAdd(&cursor[dst[e]], 1);
        esrc[pos] = src[e];
    }
}

// ---------------- neighbor aggregation: Z = (1+eps)*H + sum_{src->n} H[src] ----------------
__global__ void agg_kernel(const float* __restrict__ Hf, const int* __restrict__ indptr,
                           const int* __restrict__ esrc, const float* __restrict__ eps,
                           int layer, float* __restrict__ Z, int N) {
    int n = blockIdx.x;
    int c = threadIdx.x;
    float e1 = 1.0f + eps[layer];
    float acc = e1 * Hf[(size_t)n * H + c];
    int jb = indptr[n], je = indptr[n + 1];
    for (int j = jb; j < je; ++j) {
        int s = esrc[j];
        acc += Hf[(size_t)s * H + c];
    }
    Z[(size_t)n * H + c] = acc;
}

// ---------------- GEMM: out[N x128] = f(A)[N x128] @ W[128x128] + bias ----------------
// f(A) = relu(ca[k]*A + cc[k]) if TRANS else A.
template <bool TRANS>
__global__ __launch_bounds__(256) void gemm_kernel(
    const float* __restrict__ Af,
    const float* __restrict__ W, const float* __restrict__ bias,
    const float* __restrict__ ca, const float* __restrict__ cc,
    float* __restrict__ out, int N) {
    __shared__ float Ws[H * H];       // 64 KB
    __shared__ float As[64 * 33];     // padded to break bank conflicts
    __shared__ float cas[H], ccs[H];
    int tid = threadIdx.x;
    int tx = tid & 15, ty = tid >> 4;
    int row0 = blockIdx.x * 64;

    for (int i = tid; i < H * H; i += 256) Ws[i] = W[i];
    if (TRANS) {
        for (int i = tid; i < H; i += 256) { cas[i] = ca[i]; ccs[i] = cc[i]; }
    }
    __syncthreads();

    float acc[4][8];
#pragma unroll
    for (int r = 0; r < 4; ++r)
#pragma unroll
        for (int j = 0; j < 8; ++j) acc[r][j] = 0.f;

    for (int kk = 0; kk < 4; ++kk) {
        for (int i = tid; i < 64 * 32; i += 256) {
            int r = i >> 5, c = i & 31;
            int gr = row0 + r, k = kk * 32 + c;
            float x = 0.f;
            if (gr < N) x = Af[(size_t)gr * H + k];
            if (TRANS) x = fmaxf(cas[k] * x + ccs[k], 0.f);
            As[r * 33 + c] = x;
        }
        __syncthreads();
#pragma unroll
        for (int k2 = 0; k2 < 32; ++k2) {
            float a[4];
#pragma unroll
            for (int r = 0; r < 4; ++r) a[r] = As[(ty * 4 + r) * 33 + k2];
            const float4 w0 = *(const float4*)&Ws[(kk * 32 + k2) * H + tx * 8];
            const float4 w1 = *(const float4*)&Ws[(kk * 32 + k2) * H + tx * 8 + 4];
            float w[8] = {w0.x, w0.y, w0.z, w0.w, w1.x, w1.y, w1.z, w1.w};
#pragma unroll
            for (int r = 0; r < 4; ++r)
#pragma unroll
                for (int j = 0; j < 8; ++j) acc[r][j] = fmaf(a[r], w[j], acc[r][j]);
        }
        __syncthreads();
    }

    float bs[8];
#pragma unroll
    for (int j = 0; j < 8; ++j) bs[j] = bias[tx * 8 + j];
#pragma unroll
    for (int r = 0; r < 4; ++r) {
        int gr = row0 + ty * 4 + r;
        if (gr < N) {
            float4 o0 = {acc[r][0] + bs[0], acc[r][1] + bs[1], acc[r][2] + bs[2], acc[r][3] + bs[3]};
            float4 o1 = {acc[r][4] + bs[4], acc[r][5] + bs[5], acc[r][6] + bs[6], acc[r][7] + bs[7]};
            *(float4*)&out[(size_t)gr * H + tx * 8] = o0;
            *(float4*)&out[(size_t)gr * H + tx * 8 + 4] = o1;
        }
    }
}

// ---------------- per-column sum/sumsq ----------------
__global__ __launch_bounds__(256) void stats_kernel(const float* __restrict__ X, int N,
                                                    float* __restrict__ sum, float* __restrict__ sq) {
    int t = threadIdx.x;
    int col = t & 127, half = t >> 7;
    float s = 0.f, q = 0.f;
    for (int r = blockIdx.x * 2 + half; r < N; r += gridDim.x * 2) {
        float v = X[(size_t)r * H + col];
        s += v;
        q += v * v;
    }
    __shared__ float ls[256], lq[256];
    ls[t] = s;
    lq[t] = q;
    __syncthreads();
    if (t < 128) {
        atomicAdd(&sum[col], ls[t] + ls[t + 128]);
        atomicAdd(&sq[col], lq[t] + lq[t + 128]);
    }
}

// stats of v = relu(ca*U+cc) * snorm  (BN3 input)
__global__ __launch_bounds__(256) void statsv_kernel(const float* __restrict__ U,
                                                     const float* __restrict__ snorm,
                                                     const float* __restrict__ ca, const float* __restrict__ cc,
                                                     int N, float* __restrict__ sum, float* __restrict__ sq) {
    int t = threadIdx.x;
    int col = t & 127, half = t >> 7;
    float a = ca[col], c = cc[col];
    float s = 0.f, q = 0.f;
    for (int r = blockIdx.x * 2 + half; r < N; r += gridDim.x * 2) {
        float sn = snorm[r];
        float v = fmaxf(a * U[(size_t)r * H + col] + c, 0.f) * sn;
        s += v;
        q += v * v;
    }
    __shared__ float ls[256], lq[256];
    ls[t] = s;
    lq[t] = q;
    __syncthreads();
    if (t < 128) {
        atomicAdd(&sum[col], ls[t] + ls[t + 128]);
        atomicAdd(&sq[col], lq[t] + lq[t + 128]);
    }
}

// fold BN stats into affine coeffs; zero stats for next use
__global__ void coeff_kernel(float* __restrict__ sum, float* __restrict__ sq,
                             const float* __restrict__ gamma, const float* __restrict__ beta,
                             int N, float* __restrict__ ca, float* __restrict__ cc) {
    int c = threadIdx.x;  // 128
    float mean = sum[c] / (float)N;
    float var = sq[c] / (float)N - mean * mean;
    float inv = rsqrtf(var + 1e-5f);
    float a = gamma[c] * inv;
    ca[c] = a;
    cc[c] = beta[c] - mean * a;
    sum[c] = 0.f;
    sq[c] = 0.f;
}

// residual tail: H += relu(ca3 * (relu(ca2*U+cc2)*snorm) + cc3)
__global__ void tail_kernel(float* __restrict__ Hf, const float* __restrict__ U,
                            const float* __restrict__ snorm,
                            const float* __restrict__ ca2, const float* __restrict__ cc2,
                            const float* __restrict__ ca3, const float* __restrict__ cc3, int N) {
    int idx = blockIdx.x * blockDim.x + threadIdx.x;
    if (idx >= N * H) return;
    int r = idx >> 7, c = idx & 127;
    float v = fmaxf(ca2[c] * U[idx] + cc2[c], 0.f) * snorm[r];
    float z = fmaxf(ca3[c] * v + cc3[c], 0.f);
    Hf[idx] += z;
}

// ---------------- graph pooling ----------------
HD int lower_bound_dev(const int* __restrict__ a, int n, int key) {
    int lo = 0, hi = n;
    while (lo < hi) {
        int mid = (lo + hi) >> 1;
        if (a[mid] < key) lo = mid + 1;
        else hi = mid;
    }
    return lo;
}

__global__ void pool_kernel(const float* __restrict__ X, const int* __restrict__ gids, int N,
                            float* __restrict__ pool) {
    int g = blockIdx.x, part = blockIdx.y, c = threadIdx.x;
    int lo = lower_bound_dev(gids, N, g);
    int hi = lower_bound_dev(gids, N, g + 1);
    int len = hi - lo;
    int chunk = (len + 3) >> 2;
    int r0 = lo + part * chunk;
    int r1 = min(r0 + chunk, hi);
    float s = 0.f;
    for (int r = r0; r < r1; ++r) s += X[(size_t)r * H + c];
    atomicAdd(&pool[g * H + c], s);
}

// ---------------- final: score = sum_i pooled_i @ predW_i + predb_i ----------------
__global__ void final_kernel(const float* __restrict__ pool, const float* __restrict__ pw,
                             const float* __restrict__ pb, float* __restrict__ out) {
    int g = blockIdx.x, t = threadIdx.x;
    __shared__ float p[H];
    float acc = 0.f;
    for (int i = 0; i <= L; ++i) {
        p[t] = pool[(size_t)(i * G + g) * H + t];
        __syncthreads();
        if (t < C) {
            float s = 0.f;
            for (int f = 0; f < H; ++f) s += p[f] * pw[(size_t)(i * H + f) * C + t];
            acc += s + pb[i * C + t];
        }
        __syncthreads();
    }
    if (t < C) out[g * C + t] = acc;
}

extern "C" void kernel_launch(void* const* d_in, const int* in_sizes, int n_in,
                              void* d_out, int out_size, void* d_ws, size_t ws_size,
                              hipStream_t stream) {
    const float* h_in  = (const float*)d_in[0];
    const float* snorm = (const float*)d_in[1];
    const int* esrc_in = (const int*)d_in[2];
    const int* edst_in = (const int*)d_in[3];
    const int* gids    = (const int*)d_in[4];
    const float* embW = (const float*)d_in[5];
    const float* embB = (const float*)d_in[6];
    const float* eps  = (const float*)d_in[7];
    const float* W1   = (const float*)d_in[8];
    const float* b1   = (const float*)d_in[9];
    const float* g1   = (const float*)d_in[10];
    const float* be1  = (const float*)d_in[11];
    const float* W2   = (const float*)d_in[12];
    const float* b2   = (const float*)d_in[13];
    const float* ga   = (const float*)d_in[14];
    const float* ba   = (const float*)d_in[15];
    const float* gl   = (const float*)d_in[16];
    const float* bl   = (const float*)d_in[17];
    const float* predW = (const float*)d_in[18];
    const float* predB = (const float*)d_in[19];

    const int N = in_sizes[0] / H;  // 50000
    const int E = in_sizes[2];      // 600000

    float* ws = (float*)d_ws;
    float* Hf = ws;
    float* Z  = Hf + (size_t)N * H;
    float* T  = Z + (size_t)N * H;
    float* POOL = T + (size_t)N * H;
    float* SUM = POOL + (size_t)(L + 1) * G * H;
    float* SQ  = SUM + H;
    float* CA1 = SQ + H;  float* CC1 = CA1 + H;
    float* CA2 = CC1 + H; float* CC2 = CA2 + H;
    float* CA3 = CC2 + H; float* CC3 = CA3 + H;
    int* INDPTR = (int*)(CC3 + H);
    int* CURSOR = INDPTR + (N + 1);
    int* ESRC   = CURSOR + N;

    hipMemsetAsync(INDPTR, 0, sizeof(int) * (N + 1), stream);
    hipMemsetAsync(POOL, 0, sizeof(float) * (L + 1) * G * H, stream);
    hipMemsetAsync(SUM, 0, sizeof(float) * 2 * H, stream);

    count_kernel<<<(E + 255) / 256, 256, 0, stream>>>(edst_in, E, INDPTR);
    scan_kernel<<<1, 1024, 0, stream>>>(INDPTR, CURSOR, N);
    fill_kernel<<<(E + 255) / 256, 256, 0, stream>>>(esrc_in, edst_in, E, CURSOR, ESRC);

    int gblocks = (N + 63) / 64;
    gemm_kernel<false><<<gblocks, 256, 0, stream>>>(h_in, embW, embB, nullptr, nullptr, Hf, N);
    dim3 pg(G, 4);
    pool_kernel<<<pg, H, 0, stream>>>(Hf, gids, N, POOL);

    for (int i = 0; i < L; ++i) {
        agg_kernel<<<N, H, 0, stream>>>(Hf, INDPTR, ESRC, eps, i, Z, N);
        gemm_kernel<false><<<gblocks, 256, 0, stream>>>(Z, W1 + (size_t)i * H * H,
                                                        b1 + (size_t)i * H, nullptr, nullptr, T, N);
        stats_kernel<<<256, 256, 0, stream>>>(T, N, SUM, SQ);
        coeff_kernel<<<1, H, 0, stream>>>(SUM, SQ, g1 + (size_t)i * H, be1 + (size_t)i * H, N, CA1, CC1);
        gemm_kernel<true><<<gblocks, 256, 0, stream>>>(T, W2 + (size_t)i * H * H,
                                                       b2 + (size_t)i * H, CA1, CC1, Z, N);
        stats_kernel<<<256, 256, 0, stream>>>(Z, N, SUM, SQ);
        coeff_kernel<<<1, H, 0, stream>>>(SUM, SQ, ga + (size_t)i * H, ba + (size_t)i * H, N, CA2, CC2);
        statsv_kernel<<<256, 256, 0, stream>>>(Z, snorm, CA2, CC2, N, SUM, SQ);
        coeff_kernel<<<1, H, 0, stream>>>(SUM, SQ, gl + (size_t)i * H, bl + (size_t)i * H, N, CA3, CC3);
        tail_kernel<<<(N * H + 255) / 256, 256, 0, stream>>>(Hf, Z, snorm, CA2, CC2, CA3, CC3, N);
        pool_kernel<<<pg, H, 0, stream>>>(Hf, gids, N, POOL + (size_t)(i + 1) * G * H);
    }
    final_kernel<<<G, H, 0, stream>>>(POOL, predW, predB, (float*)d_out);
}

// Round 3
// 1196.821 us; speedup vs baseline: 1.3822x; 1.3822x over previous
//
#include <hip/hip_runtime.h>

#define HD __device__ __forceinline__

static constexpr int H = 128;
static constexpr int G = 100;
static constexpr int L = 4;
static constexpr int C = 10;
static constexpr int SCAN_NB = 100;

// ---------------- CSR build ----------------
__global__ void count_kernel(const int* __restrict__ dst, int E, int* __restrict__ indptr) {
    int e = blockIdx.x * blockDim.x + threadIdx.x;
    if (e < E) atomicAdd(&indptr[1 + dst[e]], 1);
}

// pass 1: per-block chunk sums
__global__ __launch_bounds__(256) void scan1_kernel(const int* __restrict__ P, int N, int NB,
                                                    int* __restrict__ bsum) {
    __shared__ int ls[256];
    int b = blockIdx.x, t = threadIdx.x;
    int chunk = (N + NB - 1) / NB;
    int s0 = b * chunk, s1 = min(s0 + chunk, N);
    int s = 0;
    for (int i = s0 + t; i < s1; i += 256) s += P[i];
    ls[t] = s;
    __syncthreads();
    for (int off = 128; off > 0; off >>= 1) {
        if (t < off) ls[t] += ls[t + off];
        __syncthreads();
    }
    if (t == 0) bsum[b] = ls[0];
}

// pass 2: exclusive scan of block sums (single tiny block)
__global__ void scan2_kernel(int* __restrict__ bsum, int NB) {
    __shared__ int ls[128];
    int t = threadIdx.x;
    int v = (t < NB) ? bsum[t] : 0;
    ls[t] = v;
    __syncthreads();
    for (int off = 1; off < 128; off <<= 1) {
        int u = (t >= off) ? ls[t - off] : 0;
        __syncthreads();
        ls[t] += u;
        __syncthreads();
    }
    if (t < NB) bsum[t] = (t == 0) ? 0 : ls[t - 1];
}

// pass 3: per-chunk scan with global offset; emits cursor (exclusive) and P (inclusive)
__global__ __launch_bounds__(256) void scan3_kernel(int* __restrict__ P, int* __restrict__ cursor,
                                                    const int* __restrict__ bsum, int N, int NB) {
    __shared__ int ls[256];
    int b = blockIdx.x, t = threadIdx.x;
    int chunk = (N + NB - 1) / NB;
    int sc = (chunk + 255) >> 8;
    int start = b * chunk + t * sc;
    int lim = min((b + 1) * chunk, N);
    int end = min(start + sc, lim);
    int s = 0;
    for (int g = start; g < end; ++g) s += P[g];
    ls[t] = s;
    __syncthreads();
    for (int off = 1; off < 256; off <<= 1) {
        int u = (t >= off) ? ls[t - off] : 0;
        __syncthreads();
        ls[t] += u;
        __syncthreads();
    }
    int run = bsum[b] + ((t == 0) ? 0 : ls[t - 1]);
    for (int g = start; g < end; ++g) {
        int v = P[g];
        cursor[g] = run;
        run += v;
        P[g] = run;
    }
}

__global__ void fill_kernel(const int* __restrict__ src, const int* __restrict__ dst, int E,
                            int* __restrict__ cursor, int* __restrict__ esrc) {
    int e = blockIdx.x * blockDim.x + threadIdx.x;
    if (e < E) {
        int pos = atomicAdd(&cursor[dst[e]], 1);
        esrc[pos] = src[e];
    }
}

// ---------------- neighbor aggregation: Z = (1+eps)*H + sum_{src->n} H[src] ----------------
__global__ __launch_bounds__(256) void agg_kernel(const float* __restrict__ Hf, const int* __restrict__ indptr,
                                                  const int* __restrict__ esrc, const float* __restrict__ eps,
                                                  int layer, float* __restrict__ Z, int N) {
    int node = blockIdx.x * 4 + (threadIdx.x >> 6);
    int lane = threadIdx.x & 63;
    if (node >= N) return;
    const float2* H2 = (const float2*)Hf;
    float e1 = 1.0f + eps[layer];
    float2 h = H2[(size_t)node * 64 + lane];
    float2 acc = {e1 * h.x, e1 * h.y};
    int jb = indptr[node], je = indptr[node + 1];
    int j = jb;
    for (; j + 1 < je; j += 2) {
        int s0 = esrc[j], s1 = esrc[j + 1];
        float2 v0 = H2[(size_t)s0 * 64 + lane];
        float2 v1 = H2[(size_t)s1 * 64 + lane];
        acc.x += v0.x + v1.x;
        acc.y += v0.y + v1.y;
    }
    if (j < je) {
        int s0 = esrc[j];
        float2 v0 = H2[(size_t)s0 * 64 + lane];
        acc.x += v0.x;
        acc.y += v0.y;
    }
    ((float2*)Z)[(size_t)node * 64 + lane] = acc;
}

// ---------------- GEMM: out[N x128] = f(A)[N x128] @ W[128x128] + bias ----------------
// f(A) = relu(ca[k]*A + cc[k]) if TRANS else A.
// If STATS: also atomically accumulate per-column sum/sumsq of out (valid rows only).
// Thread (tx,ty): rows ty*4..+3, cols tx*4..+3 and 64+tx*4..+3.
template <bool TRANS, bool STATS>
__global__ __launch_bounds__(256, 2) void gemm_kernel(
    const float* __restrict__ Af,
    const float* __restrict__ W, const float* __restrict__ bias,
    const float* __restrict__ ca, const float* __restrict__ cc,
    float* __restrict__ out, int N,
    float* __restrict__ sum, float* __restrict__ sq) {
    __shared__ float Ws[H * H];           // 64 KB
    __shared__ float As[64 * 36];         // 9 KB, stride 36 keeps 16B alignment, 2-way banks
    __shared__ float cas[H], ccs[H];      // 1 KB
    __shared__ float psum[4][H];          // 2 KB
    __shared__ float psq[4][H];           // 2 KB   total 79.9 KB -> 2 blocks/CU
    int tid = threadIdx.x;
    int tx = tid & 15, ty = tid >> 4;
    int lane = tid & 63, wv = tid >> 6;
    int row0 = blockIdx.x * 64;

    for (int i = tid; i < H * H; i += 256) Ws[i] = W[i];
    if (TRANS) {
        for (int i = tid; i < H; i += 256) { cas[i] = ca[i]; ccs[i] = cc[i]; }
    }
    __syncthreads();

    float acc[4][8];
#pragma unroll
    for (int r = 0; r < 4; ++r)
#pragma unroll
        for (int j = 0; j < 8; ++j) acc[r][j] = 0.f;

    for (int kk = 0; kk < 4; ++kk) {
        // stage A tile (64 rows x 32 k) as float4s
#pragma unroll
        for (int u = 0; u < 2; ++u) {
            int i = tid * 2 + u;
            int r = i >> 3, c4 = (i & 7) * 4;
            int gr = row0 + r, k = kk * 32 + c4;
            float4 x = {0.f, 0.f, 0.f, 0.f};
            if (gr < N) x = *(const float4*)&Af[(size_t)gr * H + k];
            if (TRANS) {
                x.x = fmaxf(cas[k] * x.x + ccs[k], 0.f);
                x.y = fmaxf(cas[k + 1] * x.y + ccs[k + 1], 0.f);
                x.z = fmaxf(cas[k + 2] * x.z + ccs[k + 2], 0.f);
                x.w = fmaxf(cas[k + 3] * x.w + ccs[k + 3], 0.f);
            }
            *(float4*)&As[r * 36 + c4] = x;
        }
        __syncthreads();
#pragma unroll
        for (int k2 = 0; k2 < 32; k2 += 4) {
            float4 a4[4];
#pragma unroll
            for (int r = 0; r < 4; ++r) a4[r] = *(const float4*)&As[(ty * 4 + r) * 36 + k2];
#pragma unroll
            for (int j = 0; j < 4; ++j) {
                int krow = kk * 32 + k2 + j;
                const float4 w0 = *(const float4*)&Ws[krow * H + tx * 4];
                const float4 w1 = *(const float4*)&Ws[krow * H + 64 + tx * 4];
#pragma unroll
                for (int r = 0; r < 4; ++r) {
                    float av = ((const float*)&a4[r])[j];
                    acc[r][0] = fmaf(av, w0.x, acc[r][0]);
                    acc[r][1] = fmaf(av, w0.y, acc[r][1]);
                    acc[r][2] = fmaf(av, w0.z, acc[r][2]);
                    acc[r][3] = fmaf(av, w0.w, acc[r][3]);
                    acc[r][4] = fmaf(av, w1.x, acc[r][4]);
                    acc[r][5] = fmaf(av, w1.y, acc[r][5]);
                    acc[r][6] = fmaf(av, w1.z, acc[r][6]);
                    acc[r][7] = fmaf(av, w1.w, acc[r][7]);
                }
            }
        }
        __syncthreads();
    }

    float bs[8];
#pragma unroll
    for (int j = 0; j < 4; ++j) {
        bs[j] = bias[tx * 4 + j];
        bs[4 + j] = bias[64 + tx * 4 + j];
    }
#pragma unroll
    for (int r = 0; r < 4; ++r) {
#pragma unroll
        for (int j = 0; j < 8; ++j) acc[r][j] += bs[j];
        int gr = row0 + ty * 4 + r;
        if (gr < N) {
            float4 o0 = {acc[r][0], acc[r][1], acc[r][2], acc[r][3]};
            float4 o1 = {acc[r][4], acc[r][5], acc[r][6], acc[r][7]};
            *(float4*)&out[(size_t)gr * H + tx * 4] = o0;
            *(float4*)&out[(size_t)gr * H + 64 + tx * 4] = o1;
        }
    }

    if (STATS) {
        float s[8], q[8];
#pragma unroll
        for (int j = 0; j < 8; ++j) { s[j] = 0.f; q[j] = 0.f; }
#pragma unroll
        for (int r = 0; r < 4; ++r) {
            if (row0 + ty * 4 + r < N) {
#pragma unroll
                for (int j = 0; j < 8; ++j) {
                    float v = acc[r][j];
                    s[j] += v;
                    q[j] += v * v;
                }
            }
        }
#pragma unroll
        for (int j = 0; j < 8; ++j) {
            s[j] += __shfl_xor(s[j], 16);
            s[j] += __shfl_xor(s[j], 32);
            q[j] += __shfl_xor(q[j], 16);
            q[j] += __shfl_xor(q[j], 32);
        }
        if (lane < 16) {
#pragma unroll
            for (int j = 0; j < 4; ++j) {
                psum[wv][lane * 4 + j] = s[j];
                psq[wv][lane * 4 + j] = q[j];
                psum[wv][64 + lane * 4 + j] = s[4 + j];
                psq[wv][64 + lane * 4 + j] = q[4 + j];
            }
        }
        __syncthreads();
        if (tid < H) {
            float ssum = psum[0][tid] + psum[1][tid] + psum[2][tid] + psum[3][tid];
            float ssq = psq[0][tid] + psq[1][tid] + psq[2][tid] + psq[3][tid];
            atomicAdd(&sum[tid], ssum);
            atomicAdd(&sq[tid], ssq);
        }
    }
}

// stats of v = relu(ca*U+cc) * snorm  (BN3 input)
__global__ __launch_bounds__(256) void statsv_kernel(const float* __restrict__ U,
                                                     const float* __restrict__ snorm,
                                                     const float* __restrict__ ca, const float* __restrict__ cc,
                                                     int N, float* __restrict__ sum, float* __restrict__ sq) {
    int t = threadIdx.x;
    int col = t & 127, half = t >> 7;
    float a = ca[col], c = cc[col];
    float s = 0.f, q = 0.f;
    for (int r = blockIdx.x * 2 + half; r < N; r += gridDim.x * 2) {
        float sn = snorm[r];
        float v = fmaxf(a * U[(size_t)r * H + col] + c, 0.f) * sn;
        s += v;
        q += v * v;
    }
    __shared__ float ls[256], lq[256];
    ls[t] = s;
    lq[t] = q;
    __syncthreads();
    if (t < 128) {
        atomicAdd(&sum[col], ls[t] + ls[t + 128]);
        atomicAdd(&sq[col], lq[t] + lq[t + 128]);
    }
}

// fold BN stats into affine coeffs; zero stats for next use
__global__ void coeff_kernel(float* __restrict__ sum, float* __restrict__ sq,
                             const float* __restrict__ gamma, const float* __restrict__ beta,
                             int N, float* __restrict__ ca, float* __restrict__ cc) {
    int c = threadIdx.x;  // 128
    float mean = sum[c] / (float)N;
    float var = sq[c] / (float)N - mean * mean;
    float inv = rsqrtf(var + 1e-5f);
    float a = gamma[c] * inv;
    ca[c] = a;
    cc[c] = beta[c] - mean * a;
    sum[c] = 0.f;
    sq[c] = 0.f;
}

// residual tail: H += relu(ca3 * (relu(ca2*U+cc2)*snorm) + cc3)   (float4)
__global__ void tail_kernel(float* __restrict__ Hf, const float* __restrict__ U,
                            const float* __restrict__ snorm,
                            const float* __restrict__ ca2, const float* __restrict__ cc2,
                            const float* __restrict__ ca3, const float* __restrict__ cc3, int N) {
    int idx = blockIdx.x * blockDim.x + threadIdx.x;  // over N*32 float4s
    if (idx >= N * 32) return;
    int r = idx >> 5, c4 = (idx & 31) * 4;
    float sn = snorm[r];
    float4 u = *(const float4*)&U[(size_t)r * H + c4];
    float4 h = *(float4*)&Hf[(size_t)r * H + c4];
    h.x += fmaxf(ca3[c4] * (fmaxf(ca2[c4] * u.x + cc2[c4], 0.f) * sn) + cc3[c4], 0.f);
    h.y += fmaxf(ca3[c4 + 1] * (fmaxf(ca2[c4 + 1] * u.y + cc2[c4 + 1], 0.f) * sn) + cc3[c4 + 1], 0.f);
    h.z += fmaxf(ca3[c4 + 2] * (fmaxf(ca2[c4 + 2] * u.z + cc2[c4 + 2], 0.f) * sn) + cc3[c4 + 2], 0.f);
    h.w += fmaxf(ca3[c4 + 3] * (fmaxf(ca2[c4 + 3] * u.w + cc2[c4 + 3], 0.f) * sn) + cc3[c4 + 3], 0.f);
    *(float4*)&Hf[(size_t)r * H + c4] = h;
}

// ---------------- graph pooling ----------------
HD int lower_bound_dev(const int* __restrict__ a, int n, int key) {
    int lo = 0, hi = n;
    while (lo < hi) {
        int mid = (lo + hi) >> 1;
        if (a[mid] < key) lo = mid + 1;
        else hi = mid;
    }
    return lo;
}

__global__ void pool_kernel(const float* __restrict__ X, const int* __restrict__ gids, int N,
                            float* __restrict__ pool) {
    int g = blockIdx.x, part = blockIdx.y, c = threadIdx.x;
    int lo = lower_bound_dev(gids, N, g);
    int hi = lower_bound_dev(gids, N, g + 1);
    int len = hi - lo;
    int chunk = (len + 3) >> 2;
    int r0 = lo + part * chunk;
    int r1 = min(r0 + chunk, hi);
    float s = 0.f;
    for (int r = r0; r < r1; ++r) s += X[(size_t)r * H + c];
    atomicAdd(&pool[g * H + c], s);
}

// ---------------- final: score = sum_i pooled_i @ predW_i + predb_i ----------------
__global__ void final_kernel(const float* __restrict__ pool, const float* __restrict__ pw,
                             const float* __restrict__ pb, float* __restrict__ out) {
    int g = blockIdx.x, t = threadIdx.x;
    __shared__ float p[H];
    float acc = 0.f;
    for (int i = 0; i <= L; ++i) {
        p[t] = pool[(size_t)(i * G + g) * H + t];
        __syncthreads();
        if (t < C) {
            float s = 0.f;
            for (int f = 0; f < H; ++f) s += p[f] * pw[(size_t)(i * H + f) * C + t];
            acc += s + pb[i * C + t];
        }
        __syncthreads();
    }
    if (t < C) out[g * C + t] = acc;
}

extern "C" void kernel_launch(void* const* d_in, const int* in_sizes, int n_in,
                              void* d_out, int out_size, void* d_ws, size_t ws_size,
                              hipStream_t stream) {
    const float* h_in  = (const float*)d_in[0];
    const float* snorm = (const float*)d_in[1];
    const int* esrc_in = (const int*)d_in[2];
    const int* edst_in = (const int*)d_in[3];
    const int* gids    = (const int*)d_in[4];
    const float* embW = (const float*)d_in[5];
    const float* embB = (const float*)d_in[6];
    const float* eps  = (const float*)d_in[7];
    const float* W1   = (const float*)d_in[8];
    const float* b1   = (const float*)d_in[9];
    const float* g1   = (const float*)d_in[10];
    const float* be1  = (const float*)d_in[11];
    const float* W2   = (const float*)d_in[12];
    const float* b2   = (const float*)d_in[13];
    const float* ga   = (const float*)d_in[14];
    const float* ba   = (const float*)d_in[15];
    const float* gl   = (const float*)d_in[16];
    const float* bl   = (const float*)d_in[17];
    const float* predW = (const float*)d_in[18];
    const float* predB = (const float*)d_in[19];

    const int N = in_sizes[0] / H;  // 50000
    const int E = in_sizes[2];      // 600000

    float* ws = (float*)d_ws;
    float* Hf = ws;
    float* Z  = Hf + (size_t)N * H;
    float* T  = Z + (size_t)N * H;
    float* POOL = T + (size_t)N * H;
    float* SUM = POOL + (size_t)(L + 1) * G * H;
    float* SQ  = SUM + H;
    float* CA1 = SQ + H;  float* CC1 = CA1 + H;
    float* CA2 = CC1 + H; float* CC2 = CA2 + H;
    float* CA3 = CC2 + H; float* CC3 = CA3 + H;
    int* INDPTR = (int*)(CC3 + H);
    int* CURSOR = INDPTR + (N + 1);
    int* ESRC   = CURSOR + N;
    int* BSUM   = ESRC + E;

    hipMemsetAsync(INDPTR, 0, sizeof(int) * (N + 1), stream);
    hipMemsetAsync(POOL, 0, sizeof(float) * (L + 1) * G * H, stream);
    hipMemsetAsync(SUM, 0, sizeof(float) * 2 * H, stream);

    count_kernel<<<(E + 255) / 256, 256, 0, stream>>>(edst_in, E, INDPTR);
    scan1_kernel<<<SCAN_NB, 256, 0, stream>>>(INDPTR + 1, N, SCAN_NB, BSUM);
    scan2_kernel<<<1, 128, 0, stream>>>(BSUM, SCAN_NB);
    scan3_kernel<<<SCAN_NB, 256, 0, stream>>>(INDPTR + 1, CURSOR, BSUM, N, SCAN_NB);
    fill_kernel<<<(E + 255) / 256, 256, 0, stream>>>(esrc_in, edst_in, E, CURSOR, ESRC);

    int gblocks = (N + 63) / 64;
    gemm_kernel<false, false><<<gblocks, 256, 0, stream>>>(h_in, embW, embB, nullptr, nullptr,
                                                           Hf, N, nullptr, nullptr);
    dim3 pg(G, 4);
    pool_kernel<<<pg, H, 0, stream>>>(Hf, gids, N, POOL);

    for (int i = 0; i < L; ++i) {
        agg_kernel<<<(N + 3) / 4, 256, 0, stream>>>(Hf, INDPTR, ESRC, eps, i, Z, N);
        gemm_kernel<false, true><<<gblocks, 256, 0, stream>>>(Z, W1 + (size_t)i * H * H,
                                                              b1 + (size_t)i * H, nullptr, nullptr,
                                                              T, N, SUM, SQ);
        coeff_kernel<<<1, H, 0, stream>>>(SUM, SQ, g1 + (size_t)i * H, be1 + (size_t)i * H, N, CA1, CC1);
        gemm_kernel<true, true><<<gblocks, 256, 0, stream>>>(T, W2 + (size_t)i * H * H,
                                                             b2 + (size_t)i * H, CA1, CC1,
                                                             Z, N, SUM, SQ);
        coeff_kernel<<<1, H, 0, stream>>>(SUM, SQ, ga + (size_t)i * H, ba + (size_t)i * H, N, CA2, CC2);
        statsv_kernel<<<256, 256, 0, stream>>>(Z, snorm, CA2, CC2, N, SUM, SQ);
        coeff_kernel<<<1, H, 0, stream>>>(SUM, SQ, gl + (size_t)i * H, bl + (size_t)i * H, N, CA3, CC3);
        tail_kernel<<<(N * 32 + 255) / 256, 256, 0, stream>>>(Hf, Z, snorm, CA2, CC2, CA3, CC3, N);
        pool_kernel<<<pg, H, 0, stream>>>(Hf, gids, N, POOL + (size_t)(i + 1) * G * H);
    }
    final_kernel<<<G, H, 0, stream>>>(POOL, predW, predB, (float*)d_out);
}

// Round 4
// 895.847 us; speedup vs baseline: 1.8466x; 1.3360x over previous
//
#include <hip/hip_runtime.h>

#define HD __device__ __forceinline__

static constexpr int H = 128;
static constexpr int G = 100;
static constexpr int L = 4;
static constexpr int C = 10;
static constexpr int SCAN_NB = 100;

HD float bf2f(unsigned int u16) {  // low 16 bits = bf16
    return __uint_as_float(u16 << 16);
}
HD unsigned int f2bf(float f) {    // RNE pack to 16 bits
    unsigned int u = __float_as_uint(f);
    u += 0x7fffu + ((u >> 16) & 1u);
    return u >> 16;
}

// ---------------- CSR build ----------------
__global__ void count_kernel(const int* __restrict__ dst, int E, int* __restrict__ indptr) {
    int e = blockIdx.x * blockDim.x + threadIdx.x;
    if (e < E) atomicAdd(&indptr[1 + dst[e]], 1);
}

__global__ __launch_bounds__(256) void scan1_kernel(const int* __restrict__ P, int N, int NB,
                                                    int* __restrict__ bsum) {
    __shared__ int ls[256];
    int b = blockIdx.x, t = threadIdx.x;
    int chunk = (N + NB - 1) / NB;
    int s0 = b * chunk, s1 = min(s0 + chunk, N);
    int s = 0;
    for (int i = s0 + t; i < s1; i += 256) s += P[i];
    ls[t] = s;
    __syncthreads();
    for (int off = 128; off > 0; off >>= 1) {
        if (t < off) ls[t] += ls[t + off];
        __syncthreads();
    }
    if (t == 0) bsum[b] = ls[0];
}

__global__ void scan2_kernel(int* __restrict__ bsum, int NB) {
    __shared__ int ls[128];
    int t = threadIdx.x;
    int v = (t < NB) ? bsum[t] : 0;
    ls[t] = v;
    __syncthreads();
    for (int off = 1; off < 128; off <<= 1) {
        int u = (t >= off) ? ls[t - off] : 0;
        __syncthreads();
        ls[t] += u;
        __syncthreads();
    }
    if (t < NB) bsum[t] = (t == 0) ? 0 : ls[t - 1];
}

__global__ __launch_bounds__(256) void scan3_kernel(int* __restrict__ P, int* __restrict__ cursor,
                                                    const int* __restrict__ bsum, int N, int NB) {
    __shared__ int ls[256];
    int b = blockIdx.x, t = threadIdx.x;
    int chunk = (N + NB - 1) / NB;
    int sc = (chunk + 255) >> 8;
    int start = b * chunk + t * sc;
    int lim = min((b + 1) * chunk, N);
    int end = min(start + sc, lim);
    int s = 0;
    for (int g = start; g < end; ++g) s += P[g];
    ls[t] = s;
    __syncthreads();
    for (int off = 1; off < 256; off <<= 1) {
        int u = (t >= off) ? ls[t - off] : 0;
        __syncthreads();
        ls[t] += u;
        __syncthreads();
    }
    int run = bsum[b] + ((t == 0) ? 0 : ls[t - 1]);
    for (int g = start; g < end; ++g) {
        int v = P[g];
        cursor[g] = run;
        run += v;
        P[g] = run;
    }
}

__global__ void fill_kernel(const int* __restrict__ src, const int* __restrict__ dst, int E,
                            int* __restrict__ cursor, int* __restrict__ esrc) {
    int e = blockIdx.x * blockDim.x + threadIdx.x;
    if (e < E) {
        int pos = atomicAdd(&cursor[dst[e]], 1);
        esrc[pos] = src[e];
    }
}

// ---------------- neighbor aggregation (bf16 in, bf16 out) ----------------
__global__ __launch_bounds__(256) void agg_kernel(const unsigned short* __restrict__ Hb,
                                                  const int* __restrict__ indptr,
                                                  const int* __restrict__ esrc,
                                                  const float* __restrict__ eps, int layer,
                                                  unsigned short* __restrict__ ZB, int N) {
    int node = blockIdx.x * 4 + (threadIdx.x >> 6);
    int lane = threadIdx.x & 63;
    if (node >= N) return;
    const unsigned int* H2 = (const unsigned int*)Hb;
    float e1 = 1.0f + eps[layer];
    unsigned int hv = H2[(size_t)node * 64 + lane];
    float ax = e1 * bf2f(hv & 0xffffu);
    float ay = e1 * bf2f(hv >> 16);
    int jb = indptr[node], je = indptr[node + 1];
    int j = jb;
    for (; j + 1 < je; j += 2) {
        int s0 = esrc[j], s1 = esrc[j + 1];
        unsigned int v0 = H2[(size_t)s0 * 64 + lane];
        unsigned int v1 = H2[(size_t)s1 * 64 + lane];
        ax += bf2f(v0 & 0xffffu) + bf2f(v1 & 0xffffu);
        ay += bf2f(v0 >> 16) + bf2f(v1 >> 16);
    }
    if (j < je) {
        unsigned int v0 = H2[(size_t)esrc[j] * 64 + lane];
        ax += bf2f(v0 & 0xffffu);
        ay += bf2f(v0 >> 16);
    }
    ((unsigned int*)ZB)[(size_t)node * 64 + lane] = f2bf(ax) | (f2bf(ay) << 16);
}

// ---------------- GEMM: out = f(A) @ W + bias ----------------
// ABF16: A is bf16. TRANS: f(A)=relu(ca*A+cc) with ca/cc computed inline from sum_in/sq_in.
// STATS: accumulate column sum/sumsq of out. POOLF: accumulate segment pool of out.
// OUTM: 0=f32, 1=bf16, 2=both.
template <bool ABF16, bool TRANS, bool STATS, bool POOLF, int OUTM>
__global__ __launch_bounds__(256, 2) void gemm_kernel(
    const float* __restrict__ Af, const unsigned short* __restrict__ Ab,
    const float* __restrict__ W, const float* __restrict__ bias,
    const float* __restrict__ sum_in, const float* __restrict__ sq_in,
    const float* __restrict__ gam, const float* __restrict__ bet, float invN,
    float* __restrict__ outF, unsigned short* __restrict__ outB,
    int N, float* __restrict__ sum_out, float* __restrict__ sq_out,
    const int* __restrict__ gids, float* __restrict__ pool) {
    __shared__ float Ws[H * H];                 // 64 KB
    __shared__ float As[64 * 36];               // 9 KB
    __shared__ float cas[H], ccs[H];            // 1 KB
    __shared__ float psum[4][H];                // 2 KB
    __shared__ float psq[STATS ? 4 : 1][H];     // 2 / 0.5 KB
    int tid = threadIdx.x;
    int tx = tid & 15, ty = tid >> 4;
    int lane = tid & 63, wv = tid >> 6;
    int row0 = blockIdx.x * 64;

    for (int i = tid; i < H * H; i += 256) Ws[i] = W[i];
    if (TRANS && tid < H) {
        float m = sum_in[tid] * invN;
        float var = sq_in[tid] * invN - m * m;
        float inv = rsqrtf(var + 1e-5f);
        float a = gam[tid] * inv;
        cas[tid] = a;
        ccs[tid] = bet[tid] - m * a;
    }
    __syncthreads();

    float acc[4][8];
#pragma unroll
    for (int r = 0; r < 4; ++r)
#pragma unroll
        for (int j = 0; j < 8; ++j) acc[r][j] = 0.f;

    for (int kk = 0; kk < 4; ++kk) {
        if (ABF16) {
            int r = tid >> 2, c8 = (tid & 3) * 8;
            int gr = row0 + r, k = kk * 32 + c8;
            uint4 x = {0u, 0u, 0u, 0u};
            if (gr < N) x = *(const uint4*)&Ab[(size_t)gr * H + k];
            float f[8] = {bf2f(x.x & 0xffffu), bf2f(x.x >> 16), bf2f(x.y & 0xffffu), bf2f(x.y >> 16),
                          bf2f(x.z & 0xffffu), bf2f(x.z >> 16), bf2f(x.w & 0xffffu), bf2f(x.w >> 16)};
            if (TRANS) {
#pragma unroll
                for (int j = 0; j < 8; ++j) f[j] = fmaxf(cas[k + j] * f[j] + ccs[k + j], 0.f);
            }
            float4 y0 = {f[0], f[1], f[2], f[3]};
            float4 y1 = {f[4], f[5], f[6], f[7]};
            *(float4*)&As[r * 36 + c8] = y0;
            *(float4*)&As[r * 36 + c8 + 4] = y1;
        } else {
#pragma unroll
            for (int u = 0; u < 2; ++u) {
                int i = tid * 2 + u;
                int r = i >> 3, c4 = (i & 7) * 4;
                int gr = row0 + r, k = kk * 32 + c4;
                float4 x = {0.f, 0.f, 0.f, 0.f};
                if (gr < N) x = *(const float4*)&Af[(size_t)gr * H + k];
                *(float4*)&As[r * 36 + c4] = x;
            }
        }
        __syncthreads();
#pragma unroll
        for (int k2 = 0; k2 < 32; k2 += 4) {
            float4 a4[4];
#pragma unroll
            for (int r = 0; r < 4; ++r) a4[r] = *(const float4*)&As[(ty * 4 + r) * 36 + k2];
#pragma unroll
            for (int j = 0; j < 4; ++j) {
                int krow = kk * 32 + k2 + j;
                const float4 w0 = *(const float4*)&Ws[krow * H + tx * 4];
                const float4 w1 = *(const float4*)&Ws[krow * H + 64 + tx * 4];
#pragma unroll
                for (int r = 0; r < 4; ++r) {
                    float av = ((const float*)&a4[r])[j];
                    acc[r][0] = fmaf(av, w0.x, acc[r][0]);
                    acc[r][1] = fmaf(av, w0.y, acc[r][1]);
                    acc[r][2] = fmaf(av, w0.z, acc[r][2]);
                    acc[r][3] = fmaf(av, w0.w, acc[r][3]);
                    acc[r][4] = fmaf(av, w1.x, acc[r][4]);
                    acc[r][5] = fmaf(av, w1.y, acc[r][5]);
                    acc[r][6] = fmaf(av, w1.z, acc[r][6]);
                    acc[r][7] = fmaf(av, w1.w, acc[r][7]);
                }
            }
        }
        __syncthreads();
    }

    float bs[8];
#pragma unroll
    for (int j = 0; j < 4; ++j) {
        bs[j] = bias[tx * 4 + j];
        bs[4 + j] = bias[64 + tx * 4 + j];
    }
#pragma unroll
    for (int r = 0; r < 4; ++r) {
#pragma unroll
        for (int j = 0; j < 8; ++j) acc[r][j] += bs[j];
        int gr = row0 + ty * 4 + r;
        if (gr < N) {
            if (OUTM == 0 || OUTM == 2) {
                float4 o0 = {acc[r][0], acc[r][1], acc[r][2], acc[r][3]};
                float4 o1 = {acc[r][4], acc[r][5], acc[r][6], acc[r][7]};
                *(float4*)&outF[(size_t)gr * H + tx * 4] = o0;
                *(float4*)&outF[(size_t)gr * H + 64 + tx * 4] = o1;
            }
            if (OUTM == 1 || OUTM == 2) {
                uint2 p0, p1;
                p0.x = f2bf(acc[r][0]) | (f2bf(acc[r][1]) << 16);
                p0.y = f2bf(acc[r][2]) | (f2bf(acc[r][3]) << 16);
                p1.x = f2bf(acc[r][4]) | (f2bf(acc[r][5]) << 16);
                p1.y = f2bf(acc[r][6]) | (f2bf(acc[r][7]) << 16);
                *(uint2*)&outB[(size_t)gr * H + tx * 4] = p0;
                *(uint2*)&outB[(size_t)gr * H + 64 + tx * 4] = p1;
            }
        }
    }

    if (STATS) {
        float s[8], q[8];
#pragma unroll
        for (int j = 0; j < 8; ++j) { s[j] = 0.f; q[j] = 0.f; }
#pragma unroll
        for (int r = 0; r < 4; ++r) {
            if (row0 + ty * 4 + r < N) {
#pragma unroll
                for (int j = 0; j < 8; ++j) {
                    float v = acc[r][j];
                    s[j] += v;
                    q[j] += v * v;
                }
            }
        }
#pragma unroll
        for (int j = 0; j < 8; ++j) {
            s[j] += __shfl_xor(s[j], 16);
            s[j] += __shfl_xor(s[j], 32);
            q[j] += __shfl_xor(q[j], 16);
            q[j] += __shfl_xor(q[j], 32);
        }
        if (lane < 16) {
#pragma unroll
            for (int j = 0; j < 4; ++j) {
                psum[wv][lane * 4 + j] = s[j];
                psq[wv][lane * 4 + j] = q[j];
                psum[wv][64 + lane * 4 + j] = s[4 + j];
                psq[wv][64 + lane * 4 + j] = q[4 + j];
            }
        }
        __syncthreads();
        if (tid < H) {
            atomicAdd(&sum_out[tid], psum[0][tid] + psum[1][tid] + psum[2][tid] + psum[3][tid]);
            atomicAdd(&sq_out[tid], psq[0][tid] + psq[1][tid] + psq[2][tid] + psq[3][tid]);
        }
    }

    if (POOLF) {
        int last = min(row0 + 63, N - 1);
        bool uni = (gids[row0] == gids[last]);
        if (uni) {
            float s[8];
#pragma unroll
            for (int j = 0; j < 8; ++j) s[j] = 0.f;
#pragma unroll
            for (int r = 0; r < 4; ++r) {
                if (row0 + ty * 4 + r < N) {
#pragma unroll
                    for (int j = 0; j < 8; ++j) s[j] += acc[r][j];
                }
            }
#pragma unroll
            for (int j = 0; j < 8; ++j) {
                s[j] += __shfl_xor(s[j], 16);
                s[j] += __shfl_xor(s[j], 32);
            }
            if (lane < 16) {
#pragma unroll
                for (int j = 0; j < 4; ++j) {
                    psum[wv][lane * 4 + j] = s[j];
                    psum[wv][64 + lane * 4 + j] = s[4 + j];
                }
            }
            __syncthreads();
            if (tid < H) {
                float v = psum[0][tid] + psum[1][tid] + psum[2][tid] + psum[3][tid];
                atomicAdd(&pool[gids[row0] * H + tid], v);
            }
        } else {
#pragma unroll
            for (int r = 0; r < 4; ++r) {
                int gr = row0 + ty * 4 + r;
                if (gr < N) {
                    int g = gids[gr];
#pragma unroll
                    for (int j = 0; j < 4; ++j) {
                        atomicAdd(&pool[g * H + tx * 4 + j], acc[r][j]);
                        atomicAdd(&pool[g * H + 64 + tx * 4 + j], acc[r][4 + j]);
                    }
                }
            }
        }
    }
}

// ---------------- stats of v = relu(ca*U+cc)*snorm, coeffs computed inline ----------------
__global__ __launch_bounds__(256) void statsv_kernel(const unsigned short* __restrict__ UB,
                                                     const float* __restrict__ snorm,
                                                     const float* __restrict__ sum2, const float* __restrict__ sq2,
                                                     const float* __restrict__ ga, const float* __restrict__ ba,
                                                     float invN, int N,
                                                     float* __restrict__ sum3, float* __restrict__ sq3) {
    __shared__ float cas[H], ccs[H];
    int t = threadIdx.x;
    if (t < H) {
        float m = sum2[t] * invN;
        float var = sq2[t] * invN - m * m;
        float inv = rsqrtf(var + 1e-5f);
        float a = ga[t] * inv;
        cas[t] = a;
        ccs[t] = ba[t] - m * a;
    }
    __syncthreads();
    int col2 = t & 63, part = t >> 6;
    int c0 = col2 * 2, c1 = c0 + 1;
    float a0 = cas[c0], b0 = ccs[c0], a1 = cas[c1], b1 = ccs[c1];
    float s0 = 0.f, q0 = 0.f, s1 = 0.f, q1 = 0.f;
    const unsigned int* U2 = (const unsigned int*)UB;
    for (int r = blockIdx.x * 4 + part; r < N; r += gridDim.x * 4) {
        float sn = snorm[r];
        unsigned int v = U2[(size_t)r * 64 + col2];
        float v0 = fmaxf(a0 * bf2f(v & 0xffffu) + b0, 0.f) * sn;
        float v1 = fmaxf(a1 * bf2f(v >> 16) + b1, 0.f) * sn;
        s0 += v0; q0 += v0 * v0;
        s1 += v1; q1 += v1 * v1;
    }
    __shared__ float S[4][H], Q[4][H];
    S[part][c0] = s0; S[part][c1] = s1;
    Q[part][c0] = q0; Q[part][c1] = q1;
    __syncthreads();
    if (t < H) {
        atomicAdd(&sum3[t], S[0][t] + S[1][t] + S[2][t] + S[3][t]);
        atomicAdd(&sq3[t], Q[0][t] + Q[1][t] + Q[2][t] + Q[3][t]);
    }
}

// ---------------- residual tail + bf16 mirror + fused pooling ----------------
__global__ __launch_bounds__(256) void tail_kernel(float* __restrict__ Hf, unsigned short* __restrict__ Hb,
                                                   const unsigned short* __restrict__ UB,
                                                   const float* __restrict__ snorm,
                                                   const float* __restrict__ sum2, const float* __restrict__ sq2,
                                                   const float* __restrict__ ga, const float* __restrict__ ba,
                                                   const float* __restrict__ sum3, const float* __restrict__ sq3,
                                                   const float* __restrict__ gl, const float* __restrict__ bl,
                                                   float invN, const int* __restrict__ gids,
                                                   float* __restrict__ pool, int N) {
    __shared__ float ca2[H], cc2[H], ca3[H], cc3[H];
    __shared__ float PS[8][H];
    int t = threadIdx.x;
    if (t < H) {
        float m2 = sum2[t] * invN, v2 = sq2[t] * invN - m2 * m2;
        float i2 = rsqrtf(v2 + 1e-5f), a2 = ga[t] * i2;
        ca2[t] = a2; cc2[t] = ba[t] - m2 * a2;
        float m3 = sum3[t] * invN, v3 = sq3[t] * invN - m3 * m3;
        float i3 = rsqrtf(v3 + 1e-5f), a3 = gl[t] * i3;
        ca3[t] = a3; cc3[t] = bl[t] - m3 * a3;
    }
    __syncthreads();
    int row0 = blockIdx.x * 32;
    int col4 = t & 31, rowg = t >> 5;
    int c0 = col4 * 4;
    float A2[4], B2[4], A3[4], B3[4];
#pragma unroll
    for (int j = 0; j < 4; ++j) {
        A2[j] = ca2[c0 + j]; B2[j] = cc2[c0 + j];
        A3[j] = ca3[c0 + j]; B3[j] = cc3[c0 + j];
    }
    bool uni = (gids[row0] == gids[min(row0 + 31, N - 1)]);
    float p[4] = {0.f, 0.f, 0.f, 0.f};
    const uint2* U4 = (const uint2*)UB;
#pragma unroll
    for (int rr = 0; rr < 4; ++rr) {
        int r = row0 + rowg * 4 + rr;
        if (r < N) {
            float sn = snorm[r];
            uint2 uv = U4[(size_t)r * 32 + col4];
            float u[4] = {bf2f(uv.x & 0xffffu), bf2f(uv.x >> 16), bf2f(uv.y & 0xffffu), bf2f(uv.y >> 16)};
            float4 h = *(float4*)&Hf[(size_t)r * H + c0];
            float* hp = (float*)&h;
#pragma unroll
            for (int j = 0; j < 4; ++j) {
                float v = fmaxf(A2[j] * u[j] + B2[j], 0.f) * sn;
                hp[j] += fmaxf(A3[j] * v + B3[j], 0.f);
            }
            *(float4*)&Hf[(size_t)r * H + c0] = h;
            uint2 hb;
            hb.x = f2bf(h.x) | (f2bf(h.y) << 16);
            hb.y = f2bf(h.z) | (f2bf(h.w) << 16);
            ((uint2*)Hb)[(size_t)r * 32 + col4] = hb;
            if (uni) {
                p[0] += h.x; p[1] += h.y; p[2] += h.z; p[3] += h.w;
            } else {
                int g = gids[r];
#pragma unroll
                for (int j = 0; j < 4; ++j) atomicAdd(&pool[g * H + c0 + j], hp[j]);
            }
        }
    }
    if (uni) {
#pragma unroll
        for (int j = 0; j < 4; ++j) PS[rowg][c0 + j] = p[j];
        __syncthreads();
        if (t < H) {
            float s = PS[0][t] + PS[1][t] + PS[2][t] + PS[3][t] +
                      PS[4][t] + PS[5][t] + PS[6][t] + PS[7][t];
            atomicAdd(&pool[gids[row0] * H + t], s);
        }
    }
}

// ---------------- final: score = sum_i pooled_i @ predW_i + predb_i ----------------
__global__ void final_kernel(const float* __restrict__ pool, const float* __restrict__ pw,
                             const float* __restrict__ pb, float* __restrict__ out) {
    int g = blockIdx.x, t = threadIdx.x;
    __shared__ float p[H];
    float acc = 0.f;
    for (int i = 0; i <= L; ++i) {
        p[t] = pool[(size_t)(i * G + g) * H + t];
        __syncthreads();
        if (t < C) {
            float s = 0.f;
            for (int f = 0; f < H; ++f) s += p[f] * pw[(size_t)(i * H + f) * C + t];
            acc += s + pb[i * C + t];
        }
        __syncthreads();
    }
    if (t < C) out[g * C + t] = acc;
}

extern "C" void kernel_launch(void* const* d_in, const int* in_sizes, int n_in,
                              void* d_out, int out_size, void* d_ws, size_t ws_size,
                              hipStream_t stream) {
    const float* h_in  = (const float*)d_in[0];
    const float* snorm = (const float*)d_in[1];
    const int* esrc_in = (const int*)d_in[2];
    const int* edst_in = (const int*)d_in[3];
    const int* gids    = (const int*)d_in[4];
    const float* embW = (const float*)d_in[5];
    const float* embB = (const float*)d_in[6];
    const float* eps  = (const float*)d_in[7];
    const float* W1   = (const float*)d_in[8];
    const float* b1   = (const float*)d_in[9];
    const float* g1   = (const float*)d_in[10];
    const float* be1  = (const float*)d_in[11];
    const float* W2   = (const float*)d_in[12];
    const float* b2   = (const float*)d_in[13];
    const float* ga   = (const float*)d_in[14];
    const float* ba   = (const float*)d_in[15];
    const float* gl   = (const float*)d_in[16];
    const float* bl   = (const float*)d_in[17];
    const float* predW = (const float*)d_in[18];
    const float* predB = (const float*)d_in[19];

    const int N = in_sizes[0] / H;  // 50000
    const int E = in_sizes[2];      // 600000
    const float invN = 1.0f / (float)N;

    // ws layout (16B-aligned sections)
    float* ws = (float*)d_ws;
    float* Hf = ws;                                          // N*H f32
    float* POOL = Hf + (size_t)N * H;                        // (L+1)*G*H
    float* STATS = POOL + (size_t)(L + 1) * G * H;           // L*6*H (sum1,sq1,sum2,sq2,sum3,sq3)
    int* INDPTR = (int*)(STATS + (size_t)L * 6 * H);         // N+1 (padded region to N+4)
    int* CURSOR = INDPTR + (N + 4);                          // N
    int* BSUM   = CURSOR + N;                                // SCAN_NB (100)
    int* ESRC   = BSUM + SCAN_NB;                            // E
    unsigned short* Hb = (unsigned short*)(ESRC + E);        // N*H bf16
    unsigned short* ZB = Hb + (size_t)N * H;                 // N*H bf16 (agg out / U reuse)
    unsigned short* TB = ZB + (size_t)N * H;                 // N*H bf16
    unsigned short* UB = ZB;                                 // alias: Z dead when U written

    // single memset: POOL + STATS + INDPTR
    size_t zbytes = ((size_t)(L + 1) * G * H + (size_t)L * 6 * H) * 4 + (size_t)(N + 4) * 4;
    hipMemsetAsync(POOL, 0, zbytes, stream);

    count_kernel<<<(E + 255) / 256, 256, 0, stream>>>(edst_in, E, INDPTR);
    scan1_kernel<<<SCAN_NB, 256, 0, stream>>>(INDPTR + 1, N, SCAN_NB, BSUM);
    scan2_kernel<<<1, 128, 0, stream>>>(BSUM, SCAN_NB);
    scan3_kernel<<<SCAN_NB, 256, 0, stream>>>(INDPTR + 1, CURSOR, BSUM, N, SCAN_NB);
    fill_kernel<<<(E + 255) / 256, 256, 0, stream>>>(esrc_in, edst_in, E, CURSOR, ESRC);

    int gblocks = (N + 63) / 64;
    // embedding: f32 out (Hf) + bf16 mirror (Hb) + fused pool into POOL[0]
    gemm_kernel<false, false, false, true, 2><<<gblocks, 256, 0, stream>>>(
        h_in, nullptr, embW, embB, nullptr, nullptr, nullptr, nullptr, invN,
        Hf, Hb, N, nullptr, nullptr, gids, POOL);

    for (int i = 0; i < L; ++i) {
        float* S1 = STATS + (size_t)i * 6 * H;
        float* Q1 = S1 + H;
        float* S2 = Q1 + H;
        float* Q2 = S2 + H;
        float* S3 = Q2 + H;
        float* Q3 = S3 + H;
        agg_kernel<<<(N + 3) / 4, 256, 0, stream>>>(Hb, INDPTR, ESRC, eps, i, ZB, N);
        // gemm1: A=ZB bf16, out TB bf16, stats -> S1/Q1
        gemm_kernel<true, false, true, false, 1><<<gblocks, 256, 0, stream>>>(
            nullptr, ZB, W1 + (size_t)i * H * H, b1 + (size_t)i * H,
            nullptr, nullptr, nullptr, nullptr, invN,
            nullptr, TB, N, S1, Q1, nullptr, nullptr);
        // gemm2: A=TB bf16 with BN1-affine+relu (coeffs from S1/Q1), out UB bf16, stats -> S2/Q2
        gemm_kernel<true, true, true, false, 1><<<gblocks, 256, 0, stream>>>(
            nullptr, TB, W2 + (size_t)i * H * H, b2 + (size_t)i * H,
            S1, Q1, g1 + (size_t)i * H, be1 + (size_t)i * H, invN,
            nullptr, UB, N, S2, Q2, nullptr, nullptr);
        statsv_kernel<<<256, 256, 0, stream>>>(UB, snorm, S2, Q2,
                                               ga + (size_t)i * H, ba + (size_t)i * H, invN, N, S3, Q3);
        tail_kernel<<<(N + 31) / 32, 256, 0, stream>>>(Hf, Hb, UB, snorm,
                                                       S2, Q2, ga + (size_t)i * H, ba + (size_t)i * H,
                                                       S3, Q3, gl + (size_t)i * H, bl + (size_t)i * H,
                                                       invN, gids, POOL + (size_t)(i + 1) * G * H, N);
    }
    final_kernel<<<G, H, 0, stream>>>(POOL, predW, predB, (float*)d_out);
}

// Round 5
// 799.787 us; speedup vs baseline: 2.0684x; 1.1201x over previous
//
#include <hip/hip_runtime.h>

#define HD __device__ __forceinline__

static constexpr int H = 128;
static constexpr int G = 100;
static constexpr int L = 4;
static constexpr int C = 10;
static constexpr int SCAN_NB = 100;

typedef __attribute__((ext_vector_type(8))) short short8;   // 8 bf16 (4 VGPRs)
typedef __attribute__((ext_vector_type(4))) float f32x4;    // MFMA C/D

HD float bf2f(unsigned int u16) {  // low 16 bits = bf16
    return __uint_as_float(u16 << 16);
}
HD unsigned int f2bf(float f) {    // RNE pack to 16 bits
    unsigned int u = __float_as_uint(f);
    u += 0x7fffu + ((u >> 16) & 1u);
    return u >> 16;
}

// ---------------- CSR build ----------------
__global__ void count_kernel(const int* __restrict__ dst, int E, int* __restrict__ indptr) {
    int e = blockIdx.x * blockDim.x + threadIdx.x;
    if (e < E) atomicAdd(&indptr[1 + dst[e]], 1);
}

__global__ __launch_bounds__(256) void scan1_kernel(const int* __restrict__ P, int N, int NB,
                                                    int* __restrict__ bsum) {
    __shared__ int ls[256];
    int b = blockIdx.x, t = threadIdx.x;
    int chunk = (N + NB - 1) / NB;
    int s0 = b * chunk, s1 = min(s0 + chunk, N);
    int s = 0;
    for (int i = s0 + t; i < s1; i += 256) s += P[i];
    ls[t] = s;
    __syncthreads();
    for (int off = 128; off > 0; off >>= 1) {
        if (t < off) ls[t] += ls[t + off];
        __syncthreads();
    }
    if (t == 0) bsum[b] = ls[0];
}

__global__ void scan2_kernel(int* __restrict__ bsum, int NB) {
    __shared__ int ls[128];
    int t = threadIdx.x;
    int v = (t < NB) ? bsum[t] : 0;
    ls[t] = v;
    __syncthreads();
    for (int off = 1; off < 128; off <<= 1) {
        int u = (t >= off) ? ls[t - off] : 0;
        __syncthreads();
        ls[t] += u;
        __syncthreads();
    }
    if (t < NB) bsum[t] = (t == 0) ? 0 : ls[t - 1];
}

__global__ __launch_bounds__(256) void scan3_kernel(int* __restrict__ P, int* __restrict__ cursor,
                                                    const int* __restrict__ bsum, int N, int NB) {
    __shared__ int ls[256];
    int b = blockIdx.x, t = threadIdx.x;
    int chunk = (N + NB - 1) / NB;
    int sc = (chunk + 255) >> 8;
    int start = b * chunk + t * sc;
    int lim = min((b + 1) * chunk, N);
    int end = min(start + sc, lim);
    int s = 0;
    for (int g = start; g < end; ++g) s += P[g];
    ls[t] = s;
    __syncthreads();
    for (int off = 1; off < 256; off <<= 1) {
        int u = (t >= off) ? ls[t - off] : 0;
        __syncthreads();
        ls[t] += u;
        __syncthreads();
    }
    int run = bsum[b] + ((t == 0) ? 0 : ls[t - 1]);
    for (int g = start; g < end; ++g) {
        int v = P[g];
        cursor[g] = run;
        run += v;
        P[g] = run;
    }
}

__global__ void fill_kernel(const int* __restrict__ src, const int* __restrict__ dst, int E,
                            int* __restrict__ cursor, int* __restrict__ esrc) {
    int e = blockIdx.x * blockDim.x + threadIdx.x;
    if (e < E) {
        int pos = atomicAdd(&cursor[dst[e]], 1);
        esrc[pos] = src[e];
    }
}

// ---------------- neighbor aggregation (bf16 in, bf16 out) ----------------
__global__ __launch_bounds__(256) void agg_kernel(const unsigned short* __restrict__ Hb,
                                                  const int* __restrict__ indptr,
                                                  const int* __restrict__ esrc,
                                                  const float* __restrict__ eps, int layer,
                                                  unsigned short* __restrict__ ZB, int N) {
    int node = blockIdx.x * 4 + (threadIdx.x >> 6);
    int lane = threadIdx.x & 63;
    if (node >= N) return;
    const unsigned int* H2 = (const unsigned int*)Hb;
    float e1 = 1.0f + eps[layer];
    unsigned int hv = H2[(size_t)node * 64 + lane];
    float ax = e1 * bf2f(hv & 0xffffu);
    float ay = e1 * bf2f(hv >> 16);
    int jb = indptr[node], je = indptr[node + 1];
    int j = jb;
    for (; j + 1 < je; j += 2) {
        int s0 = esrc[j], s1 = esrc[j + 1];
        unsigned int v0 = H2[(size_t)s0 * 64 + lane];
        unsigned int v1 = H2[(size_t)s1 * 64 + lane];
        ax += bf2f(v0 & 0xffffu) + bf2f(v1 & 0xffffu);
        ay += bf2f(v0 >> 16) + bf2f(v1 >> 16);
    }
    if (j < je) {
        unsigned int v0 = H2[(size_t)esrc[j] * 64 + lane];
        ax += bf2f(v0 & 0xffffu);
        ay += bf2f(v0 >> 16);
    }
    ((unsigned int*)ZB)[(size_t)node * 64 + lane] = f2bf(ax) | (f2bf(ay) << 16);
}

// ---------------- MFMA GEMM: out = f(A) @ W + bias ----------------
// Block: 256 thr / 4 waves; 64 rows x 128 cols; wave w owns cols w*32..+31.
// ABF16: A bf16 (else f32). TRANS: f(A)=relu(ca*A+cc), coeffs from sum_in/sq_in.
// STATS: column sum/sumsq of out. POOLF: segment-pool of out. OUTM: 0=f32,1=bf16,2=both.
template <bool ABF16, bool TRANS, bool STATS, bool POOLF, int OUTM>
__global__ __launch_bounds__(256, 4) void mgemm_kernel(
    const float* __restrict__ Af, const unsigned short* __restrict__ Ab,
    const float* __restrict__ W, const float* __restrict__ bias,
    const float* __restrict__ sum_in, const float* __restrict__ sq_in,
    const float* __restrict__ gam, const float* __restrict__ bet, float invN,
    float* __restrict__ outF, unsigned short* __restrict__ outB,
    int N, float* __restrict__ sum_out, float* __restrict__ sq_out,
    const int* __restrict__ gids, float* __restrict__ pool) {
    __shared__ unsigned short As[64 * 136];   // padded row stride: 272B = 17x16B
    __shared__ float cas[H], ccs[H];
    int tid = threadIdx.x;
    int w = tid >> 6, lane = tid & 63, q = lane >> 4, m = lane & 15;
    int row0 = blockIdx.x * 64;
    int colbase = w * 32;

    // ---- W -> B-fragments in registers: B[k=q*8+j][n=lane&15], bf16 ----
    short8 bfrag[2][4];
#pragma unroll
    for (int nt = 0; nt < 2; ++nt) {
        int col = colbase + nt * 16 + m;
#pragma unroll
        for (int kk = 0; kk < 4; ++kk) {
            short8 f;
#pragma unroll
            for (int j = 0; j < 8; ++j)
                f[j] = (short)f2bf(W[(size_t)(kk * 32 + q * 8 + j) * H + col]);
            bfrag[nt][kk] = f;
        }
    }

    if (TRANS) {
        if (tid < H) {
            float mu = sum_in[tid] * invN;
            float var = sq_in[tid] * invN - mu * mu;
            float inv = rsqrtf(var + 1e-5f);
            float a = gam[tid] * inv;
            cas[tid] = a;
            ccs[tid] = bet[tid] - mu * a;
        }
        __syncthreads();
    }

    // ---- stage A tile: thread = 4 rows x 8 cols ----
    {
        int cc = tid & 15, rg = tid >> 4;
        int c0 = cc * 8;
        float a8[8], b8[8];
        if (TRANS) {
#pragma unroll
            for (int j = 0; j < 8; ++j) { a8[j] = cas[c0 + j]; b8[j] = ccs[c0 + j]; }
        }
#pragma unroll
        for (int rr = 0; rr < 4; ++rr) {
            int r = rg * 4 + rr;
            int gr = row0 + r;
            uint4 o = {0u, 0u, 0u, 0u};
            if (ABF16 && !TRANS) {
                if (gr < N) o = *(const uint4*)&Ab[(size_t)gr * H + c0];
            } else {
                float v[8] = {0.f, 0.f, 0.f, 0.f, 0.f, 0.f, 0.f, 0.f};
                if (gr < N) {
                    if (ABF16) {
                        uint4 x = *(const uint4*)&Ab[(size_t)gr * H + c0];
                        v[0] = bf2f(x.x & 0xffffu); v[1] = bf2f(x.x >> 16);
                        v[2] = bf2f(x.y & 0xffffu); v[3] = bf2f(x.y >> 16);
                        v[4] = bf2f(x.z & 0xffffu); v[5] = bf2f(x.z >> 16);
                        v[6] = bf2f(x.w & 0xffffu); v[7] = bf2f(x.w >> 16);
                    } else {
                        float4 x0 = *(const float4*)&Af[(size_t)gr * H + c0];
                        float4 x1 = *(const float4*)&Af[(size_t)gr * H + c0 + 4];
                        v[0] = x0.x; v[1] = x0.y; v[2] = x0.z; v[3] = x0.w;
                        v[4] = x1.x; v[5] = x1.y; v[6] = x1.z; v[7] = x1.w;
                    }
                }
                if (TRANS) {
#pragma unroll
                    for (int j = 0; j < 8; ++j) v[j] = fmaxf(a8[j] * v[j] + b8[j], 0.f);
                }
                o.x = f2bf(v[0]) | (f2bf(v[1]) << 16);
                o.y = f2bf(v[2]) | (f2bf(v[3]) << 16);
                o.z = f2bf(v[4]) | (f2bf(v[5]) << 16);
                o.w = f2bf(v[6]) | (f2bf(v[7]) << 16);
            }
            *(uint4*)&As[r * 136 + c0] = o;
        }
    }
    __syncthreads();

    // ---- MFMA main: 4 m-tiles x 2 n-tiles x 4 k-steps ----
    f32x4 acc[4][2];
#pragma unroll
    for (int mt = 0; mt < 4; ++mt)
#pragma unroll
        for (int nt = 0; nt < 2; ++nt) acc[mt][nt] = (f32x4){0.f, 0.f, 0.f, 0.f};

#pragma unroll
    for (int kk = 0; kk < 4; ++kk) {
        short8 af[4];
#pragma unroll
        for (int mt = 0; mt < 4; ++mt)
            af[mt] = *(const short8*)&As[(mt * 16 + m) * 136 + kk * 32 + q * 8];
#pragma unroll
        for (int mt = 0; mt < 4; ++mt)
#pragma unroll
            for (int nt = 0; nt < 2; ++nt)
                acc[mt][nt] = __builtin_amdgcn_mfma_f32_16x16x32_bf16(
                    af[mt], bfrag[nt][kk], acc[mt][nt], 0, 0, 0);
    }

    // ---- epilogue: bias, stores, stats, pool ----
    float bs2[2] = {bias[colbase + m], bias[colbase + 16 + m]};
    float s[2] = {0.f, 0.f}, qq[2] = {0.f, 0.f};
#pragma unroll
    for (int mt = 0; mt < 4; ++mt) {
#pragma unroll
        for (int nt = 0; nt < 2; ++nt) {
            int gcol = colbase + nt * 16 + m;
#pragma unroll
            for (int rg = 0; rg < 4; ++rg) {
                int grow = row0 + mt * 16 + q * 4 + rg;
                float v = acc[mt][nt][rg] + bs2[nt];
                if (grow < N) {
                    if (OUTM == 0 || OUTM == 2) outF[(size_t)grow * H + gcol] = v;
                    if (OUTM == 1 || OUTM == 2) outB[(size_t)grow * H + gcol] = (unsigned short)f2bf(v);
                    if (STATS || POOLF) {
                        s[nt] += v;
                        if (STATS) qq[nt] += v * v;
                    }
                }
            }
        }
    }

    if (STATS) {
#pragma unroll
        for (int nt = 0; nt < 2; ++nt) {
            float sv = s[nt], qv = qq[nt];
            sv += __shfl_xor(sv, 16); sv += __shfl_xor(sv, 32);
            qv += __shfl_xor(qv, 16); qv += __shfl_xor(qv, 32);
            if (q == 0) {
                atomicAdd(&sum_out[colbase + nt * 16 + m], sv);
                atomicAdd(&sq_out[colbase + nt * 16 + m], qv);
            }
        }
    }

    if (POOLF) {
        int last = min(row0 + 63, N - 1);
        bool uni = (gids[row0] == gids[last]);
        if (uni) {
            int g = gids[row0];
#pragma unroll
            for (int nt = 0; nt < 2; ++nt) {
                float sv = s[nt];
                sv += __shfl_xor(sv, 16); sv += __shfl_xor(sv, 32);
                if (q == 0) atomicAdd(&pool[g * H + colbase + nt * 16 + m], sv);
            }
        } else {
#pragma unroll
            for (int mt = 0; mt < 4; ++mt)
#pragma unroll
                for (int nt = 0; nt < 2; ++nt)
#pragma unroll
                    for (int rg = 0; rg < 4; ++rg) {
                        int grow = row0 + mt * 16 + q * 4 + rg;
                        if (grow < N) {
                            float v = acc[mt][nt][rg] + bs2[nt];
                            atomicAdd(&pool[gids[grow] * H + colbase + nt * 16 + m], v);
                        }
                    }
        }
    }
}

// ---------------- stats of v = relu(ca*U+cc)*snorm, coeffs computed inline ----------------
__global__ __launch_bounds__(256) void statsv_kernel(const unsigned short* __restrict__ UB,
                                                     const float* __restrict__ snorm,
                                                     const float* __restrict__ sum2, const float* __restrict__ sq2,
                                                     const float* __restrict__ ga, const float* __restrict__ ba,
                                                     float invN, int N,
                                                     float* __restrict__ sum3, float* __restrict__ sq3) {
    __shared__ float cas[H], ccs[H];
    int t = threadIdx.x;
    if (t < H) {
        float m = sum2[t] * invN;
        float var = sq2[t] * invN - m * m;
        float inv = rsqrtf(var + 1e-5f);
        float a = ga[t] * inv;
        cas[t] = a;
        ccs[t] = ba[t] - m * a;
    }
    __syncthreads();
    int col2 = t & 63, part = t >> 6;
    int c0 = col2 * 2, c1 = c0 + 1;
    float a0 = cas[c0], b0 = ccs[c0], a1 = cas[c1], b1 = ccs[c1];
    float s0 = 0.f, q0 = 0.f, s1 = 0.f, q1 = 0.f;
    const unsigned int* U2 = (const unsigned int*)UB;
    for (int r = blockIdx.x * 4 + part; r < N; r += gridDim.x * 4) {
        float sn = snorm[r];
        unsigned int v = U2[(size_t)r * 64 + col2];
        float v0 = fmaxf(a0 * bf2f(v & 0xffffu) + b0, 0.f) * sn;
        float v1 = fmaxf(a1 * bf2f(v >> 16) + b1, 0.f) * sn;
        s0 += v0; q0 += v0 * v0;
        s1 += v1; q1 += v1 * v1;
    }
    __shared__ float S[4][H], Q[4][H];
    S[part][c0] = s0; S[part][c1] = s1;
    Q[part][c0] = q0; Q[part][c1] = q1;
    __syncthreads();
    if (t < H) {
        atomicAdd(&sum3[t], S[0][t] + S[1][t] + S[2][t] + S[3][t]);
        atomicAdd(&sq3[t], Q[0][t] + Q[1][t] + Q[2][t] + Q[3][t]);
    }
}

// ---------------- residual tail + bf16 mirror + fused pooling ----------------
__global__ __launch_bounds__(256) void tail_kernel(float* __restrict__ Hf, unsigned short* __restrict__ Hb,
                                                   const unsigned short* __restrict__ UB,
                                                   const float* __restrict__ snorm,
                                                   const float* __restrict__ sum2, const float* __restrict__ sq2,
                                                   const float* __restrict__ ga, const float* __restrict__ ba,
                                                   const float* __restrict__ sum3, const float* __restrict__ sq3,
                                                   const float* __restrict__ gl, const float* __restrict__ bl,
                                                   float invN, const int* __restrict__ gids,
                                                   float* __restrict__ pool, int N) {
    __shared__ float ca2[H], cc2[H], ca3[H], cc3[H];
    __shared__ float PS[8][H];
    int t = threadIdx.x;
    if (t < H) {
        float m2 = sum2[t] * invN, v2 = sq2[t] * invN - m2 * m2;
        float i2 = rsqrtf(v2 + 1e-5f), a2 = ga[t] * i2;
        ca2[t] = a2; cc2[t] = ba[t] - m2 * a2;
        float m3 = sum3[t] * invN, v3 = sq3[t] * invN - m3 * m3;
        float i3 = rsqrtf(v3 + 1e-5f), a3 = gl[t] * i3;
        ca3[t] = a3; cc3[t] = bl[t] - m3 * a3;
    }
    __syncthreads();
    int row0 = blockIdx.x * 32;
    int col4 = t & 31, rowg = t >> 5;
    int c0 = col4 * 4;
    float A2[4], B2[4], A3[4], B3[4];
#pragma unroll
    for (int j = 0; j < 4; ++j) {
        A2[j] = ca2[c0 + j]; B2[j] = cc2[c0 + j];
        A3[j] = ca3[c0 + j]; B3[j] = cc3[c0 + j];
    }
    bool uni = (gids[row0] == gids[min(row0 + 31, N - 1)]);
    float p[4] = {0.f, 0.f, 0.f, 0.f};
    const uint2* U4 = (const uint2*)UB;
#pragma unroll
    for (int rr = 0; rr < 4; ++rr) {
        int r = row0 + rowg * 4 + rr;
        if (r < N) {
            float sn = snorm[r];
            uint2 uv = U4[(size_t)r * 32 + col4];
            float u[4] = {bf2f(uv.x & 0xffffu), bf2f(uv.x >> 16), bf2f(uv.y & 0xffffu), bf2f(uv.y >> 16)};
            float4 h = *(float4*)&Hf[(size_t)r * H + c0];
            float* hp = (float*)&h;
#pragma unroll
            for (int j = 0; j < 4; ++j) {
                float v = fmaxf(A2[j] * u[j] + B2[j], 0.f) * sn;
                hp[j] += fmaxf(A3[j] * v + B3[j], 0.f);
            }
            *(float4*)&Hf[(size_t)r * H + c0] = h;
            uint2 hb;
            hb.x = f2bf(h.x) | (f2bf(h.y) << 16);
            hb.y = f2bf(h.z) | (f2bf(h.w) << 16);
            ((uint2*)Hb)[(size_t)r * 32 + col4] = hb;
            if (uni) {
                p[0] += h.x; p[1] += h.y; p[2] += h.z; p[3] += h.w;
            } else {
                int g = gids[r];
#pragma unroll
                for (int j = 0; j < 4; ++j) atomicAdd(&pool[g * H + c0 + j], hp[j]);
            }
        }
    }
    if (uni) {
#pragma unroll
        for (int j = 0; j < 4; ++j) PS[rowg][c0 + j] = p[j];
        __syncthreads();
        if (t < H) {
            float s = PS[0][t] + PS[1][t] + PS[2][t] + PS[3][t] +
                      PS[4][t] + PS[5][t] + PS[6][t] + PS[7][t];
            atomicAdd(&pool[gids[row0] * H + t], s);
        }
    }
}

// ---------------- final: score = sum_i pooled_i @ predW_i + predb_i ----------------
__global__ void final_kernel(const float* __restrict__ pool, const float* __restrict__ pw,
                             const float* __restrict__ pb, float* __restrict__ out) {
    int g = blockIdx.x, t = threadIdx.x;
    __shared__ float p[H];
    float acc = 0.f;
    for (int i = 0; i <= L; ++i) {
        p[t] = pool[(size_t)(i * G + g) * H + t];
        __syncthreads();
        if (t < C) {
            float s = 0.f;
            for (int f = 0; f < H; ++f) s += p[f] * pw[(size_t)(i * H + f) * C + t];
            acc += s + pb[i * C + t];
        }
        __syncthreads();
    }
    if (t < C) out[g * C + t] = acc;
}

extern "C" void kernel_launch(void* const* d_in, const int* in_sizes, int n_in,
                              void* d_out, int out_size, void* d_ws, size_t ws_size,
                              hipStream_t stream) {
    const float* h_in  = (const float*)d_in[0];
    const float* snorm = (const float*)d_in[1];
    const int* esrc_in = (const int*)d_in[2];
    const int* edst_in = (const int*)d_in[3];
    const int* gids    = (const int*)d_in[4];
    const float* embW = (const float*)d_in[5];
    const float* embB = (const float*)d_in[6];
    const float* eps  = (const float*)d_in[7];
    const float* W1   = (const float*)d_in[8];
    const float* b1   = (const float*)d_in[9];
    const float* g1   = (const float*)d_in[10];
    const float* be1  = (const float*)d_in[11];
    const float* W2   = (const float*)d_in[12];
    const float* b2   = (const float*)d_in[13];
    const float* ga   = (const float*)d_in[14];
    const float* ba   = (const float*)d_in[15];
    const float* gl   = (const float*)d_in[16];
    const float* bl   = (const float*)d_in[17];
    const float* predW = (const float*)d_in[18];
    const float* predB = (const float*)d_in[19];

    const int N = in_sizes[0] / H;  // 50000
    const int E = in_sizes[2];      // 600000
    const float invN = 1.0f / (float)N;

    // ws layout
    float* ws = (float*)d_ws;
    float* Hf = ws;                                          // N*H f32
    float* POOL = Hf + (size_t)N * H;                        // (L+1)*G*H
    float* STATS = POOL + (size_t)(L + 1) * G * H;           // L*6*H
    int* INDPTR = (int*)(STATS + (size_t)L * 6 * H);         // N+1 (pad to N+4)
    int* CURSOR = INDPTR + (N + 4);                          // N
    int* BSUM   = CURSOR + N;                                // SCAN_NB
    int* ESRC   = BSUM + SCAN_NB;                            // E
    unsigned short* Hb = (unsigned short*)(ESRC + E);        // N*H bf16
    unsigned short* ZB = Hb + (size_t)N * H;                 // N*H bf16
    unsigned short* TB = ZB + (size_t)N * H;                 // N*H bf16
    unsigned short* UB = ZB;                                 // alias: Z dead when U written

    size_t zbytes = ((size_t)(L + 1) * G * H + (size_t)L * 6 * H) * 4 + (size_t)(N + 4) * 4;
    hipMemsetAsync(POOL, 0, zbytes, stream);

    count_kernel<<<(E + 255) / 256, 256, 0, stream>>>(edst_in, E, INDPTR);
    scan1_kernel<<<SCAN_NB, 256, 0, stream>>>(INDPTR + 1, N, SCAN_NB, BSUM);
    scan2_kernel<<<1, 128, 0, stream>>>(BSUM, SCAN_NB);
    scan3_kernel<<<SCAN_NB, 256, 0, stream>>>(INDPTR + 1, CURSOR, BSUM, N, SCAN_NB);
    fill_kernel<<<(E + 255) / 256, 256, 0, stream>>>(esrc_in, edst_in, E, CURSOR, ESRC);

    int gblocks = (N + 63) / 64;
    // embedding: A=f32 h_in, out Hf f32 + Hb bf16, fused pool into POOL[0]
    mgemm_kernel<false, false, false, true, 2><<<gblocks, 256, 0, stream>>>(
        h_in, nullptr, embW, embB, nullptr, nullptr, nullptr, nullptr, invN,
        Hf, Hb, N, nullptr, nullptr, gids, POOL);

    for (int i = 0; i < L; ++i) {
        float* S1 = STATS + (size_t)i * 6 * H;
        float* Q1 = S1 + H;
        float* S2 = Q1 + H;
        float* Q2 = S2 + H;
        float* S3 = Q2 + H;
        float* Q3 = S3 + H;
        agg_kernel<<<(N + 3) / 4, 256, 0, stream>>>(Hb, INDPTR, ESRC, eps, i, ZB, N);
        // gemm1: A=ZB bf16 -> TB bf16, stats S1/Q1
        mgemm_kernel<true, false, true, false, 1><<<gblocks, 256, 0, stream>>>(
            nullptr, ZB, W1 + (size_t)i * H * H, b1 + (size_t)i * H,
            nullptr, nullptr, nullptr, nullptr, invN,
            nullptr, TB, N, S1, Q1, nullptr, nullptr);
        // gemm2: A=TB bf16 with BN1-affine+relu -> UB bf16, stats S2/Q2
        mgemm_kernel<true, true, true, false, 1><<<gblocks, 256, 0, stream>>>(
            nullptr, TB, W2 + (size_t)i * H * H, b2 + (size_t)i * H,
            S1, Q1, g1 + (size_t)i * H, be1 + (size_t)i * H, invN,
            nullptr, UB, N, S2, Q2, nullptr, nullptr);
        statsv_kernel<<<256, 256, 0, stream>>>(UB, snorm, S2, Q2,
                                               ga + (size_t)i * H, ba + (size_t)i * H, invN, N, S3, Q3);
        tail_kernel<<<(N + 31) / 32, 256, 0, stream>>>(Hf, Hb, UB, snorm,
                                                       S2, Q2, ga + (size_t)i * H, ba + (size_t)i * H,
                                                       S3, Q3, gl + (size_t)i * H, bl + (size_t)i * H,
                                                       invN, gids, POOL + (size_t)(i + 1) * G * H, N);
    }
    final_kernel<<<G, H, 0, stream>>>(POOL, predW, predB, (float*)d_out);
}

// Round 6
// 766.250 us; speedup vs baseline: 2.1589x; 1.0438x over previous
//
#include <hip/hip_runtime.h>

#define HD __device__ __forceinline__

static constexpr int H = 128;
static constexpr int G = 100;
static constexpr int L = 4;
static constexpr int C = 10;
static constexpr int SCAN_NB = 100;

typedef __attribute__((ext_vector_type(8))) short short8;   // 8 bf16 (4 VGPRs)
typedef __attribute__((ext_vector_type(4))) float f32x4;    // MFMA C/D

HD float bf2f(unsigned int u16) {  // low 16 bits = bf16
    return __uint_as_float(u16 << 16);
}
HD unsigned int f2bf(float f) {    // RNE pack to 16 bits
    unsigned int u = __float_as_uint(f);
    u += 0x7fffu + ((u >> 16) & 1u);
    return u >> 16;
}

// ---------------- weight prep: f32 row-major W[k][col] -> bf16 col-major WT[col][k] ----------------
// mat 0 = embW, 1..L = W1[i], L+1..2L = W2[i]
__global__ __launch_bounds__(256) void wprep_kernel(const float* __restrict__ embW,
                                                    const float* __restrict__ W1,
                                                    const float* __restrict__ W2,
                                                    unsigned short* __restrict__ WT) {
    int mat = blockIdx.y;
    const float* src = (mat == 0) ? embW
                     : (mat <= L) ? W1 + (size_t)(mat - 1) * H * H
                                  : W2 + (size_t)(mat - 1 - L) * H * H;
    int t = blockIdx.x * 256 + threadIdx.x;   // 0..16383
    int col = t >> 7, k = t & 127;
    WT[(size_t)mat * H * H + col * H + k] = (unsigned short)f2bf(src[(size_t)k * H + col]);
}

// ---------------- CSR build ----------------
__global__ void count_kernel(const int* __restrict__ dst, int E, int* __restrict__ indptr) {
    int e = blockIdx.x * blockDim.x + threadIdx.x;
    if (e < E) atomicAdd(&indptr[1 + dst[e]], 1);
}

__global__ __launch_bounds__(256) void scan1_kernel(const int* __restrict__ P, int N, int NB,
                                                    int* __restrict__ bsum) {
    __shared__ int ls[256];
    int b = blockIdx.x, t = threadIdx.x;
    int chunk = (N + NB - 1) / NB;
    int s0 = b * chunk, s1 = min(s0 + chunk, N);
    int s = 0;
    for (int i = s0 + t; i < s1; i += 256) s += P[i];
    ls[t] = s;
    __syncthreads();
    for (int off = 128; off > 0; off >>= 1) {
        if (t < off) ls[t] += ls[t + off];
        __syncthreads();
    }
    if (t == 0) bsum[b] = ls[0];
}

__global__ void scan2_kernel(int* __restrict__ bsum, int NB) {
    __shared__ int ls[128];
    int t = threadIdx.x;
    int v = (t < NB) ? bsum[t] : 0;
    ls[t] = v;
    __syncthreads();
    for (int off = 1; off < 128; off <<= 1) {
        int u = (t >= off) ? ls[t - off] : 0;
        __syncthreads();
        ls[t] += u;
        __syncthreads();
    }
    if (t < NB) bsum[t] = (t == 0) ? 0 : ls[t - 1];
}

__global__ __launch_bounds__(256) void scan3_kernel(int* __restrict__ P, int* __restrict__ cursor,
                                                    const int* __restrict__ bsum, int N, int NB) {
    __shared__ int ls[256];
    int b = blockIdx.x, t = threadIdx.x;
    int chunk = (N + NB - 1) / NB;
    int sc = (chunk + 255) >> 8;
    int start = b * chunk + t * sc;
    int lim = min((b + 1) * chunk, N);
    int end = min(start + sc, lim);
    int s = 0;
    for (int g = start; g < end; ++g) s += P[g];
    ls[t] = s;
    __syncthreads();
    for (int off = 1; off < 256; off <<= 1) {
        int u = (t >= off) ? ls[t - off] : 0;
        __syncthreads();
        ls[t] += u;
        __syncthreads();
    }
    int run = bsum[b] + ((t == 0) ? 0 : ls[t - 1]);
    for (int g = start; g < end; ++g) {
        int v = P[g];
        cursor[g] = run;
        run += v;
        P[g] = run;
    }
}

__global__ void fill_kernel(const int* __restrict__ src, const int* __restrict__ dst, int E,
                            int* __restrict__ cursor, int* __restrict__ esrc) {
    int e = blockIdx.x * blockDim.x + threadIdx.x;
    if (e < E) {
        int pos = atomicAdd(&cursor[dst[e]], 1);
        esrc[pos] = src[e];
    }
}

// ---------------- neighbor aggregation (bf16 in, bf16 out), 4 independent gather chains ----------------
__global__ __launch_bounds__(256) void agg_kernel(const unsigned short* __restrict__ Hb,
                                                  const int* __restrict__ indptr,
                                                  const int* __restrict__ esrc,
                                                  const float* __restrict__ eps, int layer,
                                                  unsigned short* __restrict__ ZB, int N) {
    int node = blockIdx.x * 4 + (threadIdx.x >> 6);
    int lane = threadIdx.x & 63;
    if (node >= N) return;
    const unsigned int* H2 = (const unsigned int*)Hb;
    float e1 = 1.0f + eps[layer];
    unsigned int hv = H2[(size_t)node * 64 + lane];
    float ax0 = e1 * bf2f(hv & 0xffffu), ay0 = e1 * bf2f(hv >> 16);
    float ax1 = 0.f, ay1 = 0.f, ax2 = 0.f, ay2 = 0.f, ax3 = 0.f, ay3 = 0.f;
    int jb = indptr[node], je = indptr[node + 1];
    int j = jb;
    for (; j + 3 < je; j += 4) {
        int s0 = esrc[j], s1 = esrc[j + 1], s2 = esrc[j + 2], s3 = esrc[j + 3];
        unsigned int v0 = H2[(size_t)s0 * 64 + lane];
        unsigned int v1 = H2[(size_t)s1 * 64 + lane];
        unsigned int v2 = H2[(size_t)s2 * 64 + lane];
        unsigned int v3 = H2[(size_t)s3 * 64 + lane];
        ax0 += bf2f(v0 & 0xffffu); ay0 += bf2f(v0 >> 16);
        ax1 += bf2f(v1 & 0xffffu); ay1 += bf2f(v1 >> 16);
        ax2 += bf2f(v2 & 0xffffu); ay2 += bf2f(v2 >> 16);
        ax3 += bf2f(v3 & 0xffffu); ay3 += bf2f(v3 >> 16);
    }
    for (; j < je; ++j) {
        unsigned int v0 = H2[(size_t)esrc[j] * 64 + lane];
        ax0 += bf2f(v0 & 0xffffu); ay0 += bf2f(v0 >> 16);
    }
    float ax = (ax0 + ax1) + (ax2 + ax3);
    float ay = (ay0 + ay1) + (ay2 + ay3);
    ((unsigned int*)ZB)[(size_t)node * 64 + lane] = f2bf(ax) | (f2bf(ay) << 16);
}

// ---------------- MFMA GEMM: out = f(A) @ W + bias ----------------
// Block: 256 thr / 4 waves; 64 rows x 128 cols; wave w owns cols w*32..+31.
// WT is bf16 col-major [col*128 + k]. ABF16: A bf16 (else f32).
// TRANS: f(A)=relu(ca*A+cc), coeffs from sum_in/sq_in.
// STATS: column sum/sumsq of out. POOLF: segment-pool of out. OUTM: 0=f32,1=bf16,2=both.
template <bool ABF16, bool TRANS, bool STATS, bool POOLF, int OUTM>
__global__ __launch_bounds__(256, 4) void mgemm_kernel(
    const float* __restrict__ Af, const unsigned short* __restrict__ Ab,
    const unsigned short* __restrict__ WT, const float* __restrict__ bias,
    const float* __restrict__ sum_in, const float* __restrict__ sq_in,
    const float* __restrict__ gam, const float* __restrict__ bet, float invN,
    float* __restrict__ outF, unsigned short* __restrict__ outB,
    int N, float* __restrict__ sum_out, float* __restrict__ sq_out,
    const int* __restrict__ gids, float* __restrict__ pool) {
    __shared__ unsigned short As[64 * 136];   // padded row stride: 272B = 17x16B
    __shared__ float cas[H], ccs[H];
    int tid = threadIdx.x;
    int w = tid >> 6, lane = tid & 63, q = lane >> 4, m = lane & 15;
    int row0 = blockIdx.x * 64;
    int colbase = w * 32;

    // ---- W -> B-fragments: one 16B load per fragment from col-major bf16 WT ----
    short8 bfrag[2][4];
#pragma unroll
    for (int nt = 0; nt < 2; ++nt) {
        const unsigned short* wc = WT + (size_t)(colbase + nt * 16 + m) * H;
#pragma unroll
        for (int kk = 0; kk < 4; ++kk)
            bfrag[nt][kk] = *(const short8*)&wc[kk * 32 + q * 8];
    }

    if (TRANS) {
        if (tid < H) {
            float mu = sum_in[tid] * invN;
            float var = sq_in[tid] * invN - mu * mu;
            float inv = rsqrtf(var + 1e-5f);
            float a = gam[tid] * inv;
            cas[tid] = a;
            ccs[tid] = bet[tid] - mu * a;
        }
        __syncthreads();
    }

    // ---- stage A tile: thread = 4 rows x 8 cols ----
    {
        int cc = tid & 15, rg = tid >> 4;
        int c0 = cc * 8;
        float a8[8], b8[8];
        if (TRANS) {
#pragma unroll
            for (int j = 0; j < 8; ++j) { a8[j] = cas[c0 + j]; b8[j] = ccs[c0 + j]; }
        }
#pragma unroll
        for (int rr = 0; rr < 4; ++rr) {
            int r = rg * 4 + rr;
            int gr = row0 + r;
            uint4 o = {0u, 0u, 0u, 0u};
            if (ABF16 && !TRANS) {
                if (gr < N) o = *(const uint4*)&Ab[(size_t)gr * H + c0];
            } else {
                float v[8] = {0.f, 0.f, 0.f, 0.f, 0.f, 0.f, 0.f, 0.f};
                if (gr < N) {
                    if (ABF16) {
                        uint4 x = *(const uint4*)&Ab[(size_t)gr * H + c0];
                        v[0] = bf2f(x.x & 0xffffu); v[1] = bf2f(x.x >> 16);
                        v[2] = bf2f(x.y & 0xffffu); v[3] = bf2f(x.y >> 16);
                        v[4] = bf2f(x.z & 0xffffu); v[5] = bf2f(x.z >> 16);
                        v[6] = bf2f(x.w & 0xffffu); v[7] = bf2f(x.w >> 16);
                    } else {
                        float4 x0 = *(const float4*)&Af[(size_t)gr * H + c0];
                        float4 x1 = *(const float4*)&Af[(size_t)gr * H + c0 + 4];
                        v[0] = x0.x; v[1] = x0.y; v[2] = x0.z; v[3] = x0.w;
                        v[4] = x1.x; v[5] = x1.y; v[6] = x1.z; v[7] = x1.w;
                    }
                }
                if (TRANS) {
#pragma unroll
                    for (int j = 0; j < 8; ++j) v[j] = fmaxf(a8[j] * v[j] + b8[j], 0.f);
                }
                o.x = f2bf(v[0]) | (f2bf(v[1]) << 16);
                o.y = f2bf(v[2]) | (f2bf(v[3]) << 16);
                o.z = f2bf(v[4]) | (f2bf(v[5]) << 16);
                o.w = f2bf(v[6]) | (f2bf(v[7]) << 16);
            }
            *(uint4*)&As[r * 136 + c0] = o;
        }
    }
    __syncthreads();

    // ---- MFMA main: 4 m-tiles x 2 n-tiles x 4 k-steps ----
    f32x4 acc[4][2];
#pragma unroll
    for (int mt = 0; mt < 4; ++mt)
#pragma unroll
        for (int nt = 0; nt < 2; ++nt) acc[mt][nt] = (f32x4){0.f, 0.f, 0.f, 0.f};

#pragma unroll
    for (int kk = 0; kk < 4; ++kk) {
        short8 af[4];
#pragma unroll
        for (int mt = 0; mt < 4; ++mt)
            af[mt] = *(const short8*)&As[(mt * 16 + m) * 136 + kk * 32 + q * 8];
#pragma unroll
        for (int mt = 0; mt < 4; ++mt)
#pragma unroll
            for (int nt = 0; nt < 2; ++nt)
                acc[mt][nt] = __builtin_amdgcn_mfma_f32_16x16x32_bf16(
                    af[mt], bfrag[nt][kk], acc[mt][nt], 0, 0, 0);
    }

    // ---- epilogue: bias, stores, stats, pool ----
    float bs2[2] = {bias[colbase + m], bias[colbase + 16 + m]};
    float s[2] = {0.f, 0.f}, qq[2] = {0.f, 0.f};
#pragma unroll
    for (int mt = 0; mt < 4; ++mt) {
#pragma unroll
        for (int nt = 0; nt < 2; ++nt) {
            int gcol = colbase + nt * 16 + m;
#pragma unroll
            for (int rg = 0; rg < 4; ++rg) {
                int grow = row0 + mt * 16 + q * 4 + rg;
                float v = acc[mt][nt][rg] + bs2[nt];
                if (grow < N) {
                    if (OUTM == 0 || OUTM == 2) outF[(size_t)grow * H + gcol] = v;
                    if (OUTM == 1 || OUTM == 2) outB[(size_t)grow * H + gcol] = (unsigned short)f2bf(v);
                    if (STATS || POOLF) {
                        s[nt] += v;
                        if (STATS) qq[nt] += v * v;
                    }
                }
            }
        }
    }

    if (STATS) {
#pragma unroll
        for (int nt = 0; nt < 2; ++nt) {
            float sv = s[nt], qv = qq[nt];
            sv += __shfl_xor(sv, 16); sv += __shfl_xor(sv, 32);
            qv += __shfl_xor(qv, 16); qv += __shfl_xor(qv, 32);
            if (q == 0) {
                atomicAdd(&sum_out[colbase + nt * 16 + m], sv);
                atomicAdd(&sq_out[colbase + nt * 16 + m], qv);
            }
        }
    }

    if (POOLF) {
        int last = min(row0 + 63, N - 1);
        bool uni = (gids[row0] == gids[last]);
        if (uni) {
            int g = gids[row0];
#pragma unroll
            for (int nt = 0; nt < 2; ++nt) {
                float sv = s[nt];
                sv += __shfl_xor(sv, 16); sv += __shfl_xor(sv, 32);
                if (q == 0) atomicAdd(&pool[g * H + colbase + nt * 16 + m], sv);
            }
        } else {
#pragma unroll
            for (int mt = 0; mt < 4; ++mt)
#pragma unroll
                for (int nt = 0; nt < 2; ++nt)
#pragma unroll
                    for (int rg = 0; rg < 4; ++rg) {
                        int grow = row0 + mt * 16 + q * 4 + rg;
                        if (grow < N) {
                            float v = acc[mt][nt][rg] + bs2[nt];
                            atomicAdd(&pool[gids[grow] * H + colbase + nt * 16 + m], v);
                        }
                    }
        }
    }
}

// ---------------- stats of v = relu(ca*U+cc)*snorm, coeffs computed inline ----------------
__global__ __launch_bounds__(256) void statsv_kernel(const unsigned short* __restrict__ UB,
                                                     const float* __restrict__ snorm,
                                                     const float* __restrict__ sum2, const float* __restrict__ sq2,
                                                     const float* __restrict__ ga, const float* __restrict__ ba,
                                                     float invN, int N,
                                                     float* __restrict__ sum3, float* __restrict__ sq3) {
    __shared__ float cas[H], ccs[H];
    int t = threadIdx.x;
    if (t < H) {
        float m = sum2[t] * invN;
        float var = sq2[t] * invN - m * m;
        float inv = rsqrtf(var + 1e-5f);
        float a = ga[t] * inv;
        cas[t] = a;
        ccs[t] = ba[t] - m * a;
    }
    __syncthreads();
    int col2 = t & 63, part = t >> 6;
    int c0 = col2 * 2, c1 = c0 + 1;
    float a0 = cas[c0], b0 = ccs[c0], a1 = cas[c1], b1 = ccs[c1];
    float s0 = 0.f, q0 = 0.f, s1 = 0.f, q1 = 0.f;
    const unsigned int* U2 = (const unsigned int*)UB;
    for (int r = blockIdx.x * 4 + part; r < N; r += gridDim.x * 4) {
        float sn = snorm[r];
        unsigned int v = U2[(size_t)r * 64 + col2];
        float v0 = fmaxf(a0 * bf2f(v & 0xffffu) + b0, 0.f) * sn;
        float v1 = fmaxf(a1 * bf2f(v >> 16) + b1, 0.f) * sn;
        s0 += v0; q0 += v0 * v0;
        s1 += v1; q1 += v1 * v1;
    }
    __shared__ float S[4][H], Q[4][H];
    S[part][c0] = s0; S[part][c1] = s1;
    Q[part][c0] = q0; Q[part][c1] = q1;
    __syncthreads();
    if (t < H) {
        atomicAdd(&sum3[t], S[0][t] + S[1][t] + S[2][t] + S[3][t]);
        atomicAdd(&sq3[t], Q[0][t] + Q[1][t] + Q[2][t] + Q[3][t]);
    }
}

// ---------------- residual tail + bf16 mirror + fused pooling ----------------
__global__ __launch_bounds__(256) void tail_kernel(float* __restrict__ Hf, unsigned short* __restrict__ Hb,
                                                   const unsigned short* __restrict__ UB,
                                                   const float* __restrict__ snorm,
                                                   const float* __restrict__ sum2, const float* __restrict__ sq2,
                                                   const float* __restrict__ ga, const float* __restrict__ ba,
                                                   const float* __restrict__ sum3, const float* __restrict__ sq3,
                                                   const float* __restrict__ gl, const float* __restrict__ bl,
                                                   float invN, const int* __restrict__ gids,
                                                   float* __restrict__ pool, int N) {
    __shared__ float ca2[H], cc2[H], ca3[H], cc3[H];
    __shared__ float PS[8][H];
    int t = threadIdx.x;
    if (t < H) {
        float m2 = sum2[t] * invN, v2 = sq2[t] * invN - m2 * m2;
        float i2 = rsqrtf(v2 + 1e-5f), a2 = ga[t] * i2;
        ca2[t] = a2; cc2[t] = ba[t] - m2 * a2;
        float m3 = sum3[t] * invN, v3 = sq3[t] * invN - m3 * m3;
        float i3 = rsqrtf(v3 + 1e-5f), a3 = gl[t] * i3;
        ca3[t] = a3; cc3[t] = bl[t] - m3 * a3;
    }
    __syncthreads();
    int row0 = blockIdx.x * 32;
    int col4 = t & 31, rowg = t >> 5;
    int c0 = col4 * 4;
    float A2[4], B2[4], A3[4], B3[4];
#pragma unroll
    for (int j = 0; j < 4; ++j) {
        A2[j] = ca2[c0 + j]; B2[j] = cc2[c0 + j];
        A3[j] = ca3[c0 + j]; B3[j] = cc3[c0 + j];
    }
    bool uni = (gids[row0] == gids[min(row0 + 31, N - 1)]);
    float p[4] = {0.f, 0.f, 0.f, 0.f};
    const uint2* U4 = (const uint2*)UB;
#pragma unroll
    for (int rr = 0; rr < 4; ++rr) {
        int r = row0 + rowg * 4 + rr;
        if (r < N) {
            float sn = snorm[r];
            uint2 uv = U4[(size_t)r * 32 + col4];
            float u[4] = {bf2f(uv.x & 0xffffu), bf2f(uv.x >> 16), bf2f(uv.y & 0xffffu), bf2f(uv.y >> 16)};
            float4 h = *(float4*)&Hf[(size_t)r * H + c0];
            float* hp = (float*)&h;
#pragma unroll
            for (int j = 0; j < 4; ++j) {
                float v = fmaxf(A2[j] * u[j] + B2[j], 0.f) * sn;
                hp[j] += fmaxf(A3[j] * v + B3[j], 0.f);
            }
            *(float4*)&Hf[(size_t)r * H + c0] = h;
            uint2 hb;
            hb.x = f2bf(h.x) | (f2bf(h.y) << 16);
            hb.y = f2bf(h.z) | (f2bf(h.w) << 16);
            ((uint2*)Hb)[(size_t)r * 32 + col4] = hb;
            if (uni) {
                p[0] += h.x; p[1] += h.y; p[2] += h.z; p[3] += h.w;
            } else {
                int g = gids[r];
#pragma unroll
                for (int j = 0; j < 4; ++j) atomicAdd(&pool[g * H + c0 + j], hp[j]);
            }
        }
    }
    if (uni) {
#pragma unroll
        for (int j = 0; j < 4; ++j) PS[rowg][c0 + j] = p[j];
        __syncthreads();
        if (t < H) {
            float s = PS[0][t] + PS[1][t] + PS[2][t] + PS[3][t] +
                      PS[4][t] + PS[5][t] + PS[6][t] + PS[7][t];
            atomicAdd(&pool[gids[row0] * H + t], s);
        }
    }
}

// ---------------- final: score = sum_i pooled_i @ predW_i + predb_i ----------------
__global__ void final_kernel(const float* __restrict__ pool, const float* __restrict__ pw,
                             const float* __restrict__ pb, float* __restrict__ out) {
    int g = blockIdx.x, t = threadIdx.x;
    __shared__ float p[H];
    float acc = 0.f;
    for (int i = 0; i <= L; ++i) {
        p[t] = pool[(size_t)(i * G + g) * H + t];
        __syncthreads();
        if (t < C) {
            float s = 0.f;
            for (int f = 0; f < H; ++f) s += p[f] * pw[(size_t)(i * H + f) * C + t];
            acc += s + pb[i * C + t];
        }
        __syncthreads();
    }
    if (t < C) out[g * C + t] = acc;
}

extern "C" void kernel_launch(void* const* d_in, const int* in_sizes, int n_in,
                              void* d_out, int out_size, void* d_ws, size_t ws_size,
                              hipStream_t stream) {
    const float* h_in  = (const float*)d_in[0];
    const float* snorm = (const float*)d_in[1];
    const int* esrc_in = (const int*)d_in[2];
    const int* edst_in = (const int*)d_in[3];
    const int* gids    = (const int*)d_in[4];
    const float* embW = (const float*)d_in[5];
    const float* embB = (const float*)d_in[6];
    const float* eps  = (const float*)d_in[7];
    const float* W1   = (const float*)d_in[8];
    const float* b1   = (const float*)d_in[9];
    const float* g1   = (const float*)d_in[10];
    const float* be1  = (const float*)d_in[11];
    const float* W2   = (const float*)d_in[12];
    const float* b2   = (const float*)d_in[13];
    const float* ga   = (const float*)d_in[14];
    const float* ba   = (const float*)d_in[15];
    const float* gl   = (const float*)d_in[16];
    const float* bl   = (const float*)d_in[17];
    const float* predW = (const float*)d_in[18];
    const float* predB = (const float*)d_in[19];

    const int N = in_sizes[0] / H;  // 50000
    const int E = in_sizes[2];      // 600000
    const float invN = 1.0f / (float)N;

    // ws layout (all sections 16B-aligned by construction)
    float* ws = (float*)d_ws;
    float* Hf = ws;                                          // N*H f32
    float* POOL = Hf + (size_t)N * H;                        // (L+1)*G*H
    float* STATS = POOL + (size_t)(L + 1) * G * H;           // L*6*H
    unsigned short* WT = (unsigned short*)(STATS + (size_t)L * 6 * H);  // 9*H*H bf16
    int* INDPTR = (int*)(WT + (size_t)9 * H * H);            // N+1 (pad to N+4)
    int* CURSOR = INDPTR + (N + 4);                          // N
    int* BSUM   = CURSOR + N;                                // SCAN_NB
    int* ESRC   = BSUM + SCAN_NB;                            // E
    unsigned short* Hb = (unsigned short*)(ESRC + E);        // N*H bf16
    unsigned short* ZB = Hb + (size_t)N * H;                 // N*H bf16
    unsigned short* TB = ZB + (size_t)N * H;                 // N*H bf16
    unsigned short* UB = ZB;                                 // alias: Z dead when U written

    size_t zbytes = ((size_t)(L + 1) * G * H + (size_t)L * 6 * H) * 4
                  + (size_t)9 * H * H * 2 + (size_t)(N + 4) * 4;
    hipMemsetAsync(POOL, 0, zbytes, stream);

    wprep_kernel<<<dim3(64, 9), 256, 0, stream>>>(embW, W1, W2, WT);
    count_kernel<<<(E + 255) / 256, 256, 0, stream>>>(edst_in, E, INDPTR);
    scan1_kernel<<<SCAN_NB, 256, 0, stream>>>(INDPTR + 1, N, SCAN_NB, BSUM);
    scan2_kernel<<<1, 128, 0, stream>>>(BSUM, SCAN_NB);
    scan3_kernel<<<SCAN_NB, 256, 0, stream>>>(INDPTR + 1, CURSOR, BSUM, N, SCAN_NB);
    fill_kernel<<<(E + 255) / 256, 256, 0, stream>>>(esrc_in, edst_in, E, CURSOR, ESRC);

    int gblocks = (N + 63) / 64;
    // embedding: A=f32 h_in, out Hf f32 + Hb bf16, fused pool into POOL[0]
    mgemm_kernel<false, false, false, true, 2><<<gblocks, 256, 0, stream>>>(
        h_in, nullptr, WT, embB, nullptr, nullptr, nullptr, nullptr, invN,
        Hf, Hb, N, nullptr, nullptr, gids, POOL);

    for (int i = 0; i < L; ++i) {
        float* S1 = STATS + (size_t)i * 6 * H;
        float* Q1 = S1 + H;
        float* S2 = Q1 + H;
        float* Q2 = S2 + H;
        float* S3 = Q2 + H;
        float* Q3 = S3 + H;
        agg_kernel<<<(N + 3) / 4, 256, 0, stream>>>(Hb, INDPTR, ESRC, eps, i, ZB, N);
        // gemm1: A=ZB bf16 -> TB bf16, stats S1/Q1
        mgemm_kernel<true, false, true, false, 1><<<gblocks, 256, 0, stream>>>(
            nullptr, ZB, WT + (size_t)(1 + i) * H * H, b1 + (size_t)i * H,
            nullptr, nullptr, nullptr, nullptr, invN,
            nullptr, TB, N, S1, Q1, nullptr, nullptr);
        // gemm2: A=TB bf16 with BN1-affine+relu -> UB bf16, stats S2/Q2
        mgemm_kernel<true, true, true, false, 1><<<gblocks, 256, 0, stream>>>(
            nullptr, TB, WT + (size_t)(1 + L + i) * H * H, b2 + (size_t)i * H,
            S1, Q1, g1 + (size_t)i * H, be1 + (size_t)i * H, invN,
            nullptr, UB, N, S2, Q2, nullptr, nullptr);
        statsv_kernel<<<256, 256, 0, stream>>>(UB, snorm, S2, Q2,
                                               ga + (size_t)i * H, ba + (size_t)i * H, invN, N, S3, Q3);
        tail_kernel<<<(N + 31) / 32, 256, 0, stream>>>(Hf, Hb, UB, snorm,
                                                       S2, Q2, ga + (size_t)i * H, ba + (size_t)i * H,
                                                       S3, Q3, gl + (size_t)i * H, bl + (size_t)i * H,
                                                       invN, gids, POOL + (size_t)(i + 1) * G * H, N);
    }
    final_kernel<<<G, H, 0, stream>>>(POOL, predW, predB, (float*)d_out);
}

// Round 7
// 732.968 us; speedup vs baseline: 2.2569x; 1.0454x over previous
//
#include <hip/hip_runtime.h>

#define HD __device__ __forceinline__

static constexpr int H = 128;
static constexpr int G = 100;
static constexpr int L = 4;
static constexpr int C = 10;
static constexpr int SCAN_NB = 100;

typedef __attribute__((ext_vector_type(8))) short short8;   // 8 bf16 (4 VGPRs)
typedef __attribute__((ext_vector_type(4))) float f32x4;    // MFMA C/D

HD float bf2f(unsigned int u16) {  // low 16 bits = bf16
    return __uint_as_float(u16 << 16);
}
HD unsigned int f2bf(float f) {    // RNE pack to 16 bits
    unsigned int u = __float_as_uint(f);
    u += 0x7fffu + ((u >> 16) & 1u);
    return u >> 16;
}

// ---------------- weight prep: f32 row-major W[k][col] -> bf16 col-major WT[col][k] ----------------
__global__ __launch_bounds__(256) void wprep_kernel(const float* __restrict__ embW,
                                                    const float* __restrict__ W1,
                                                    const float* __restrict__ W2,
                                                    unsigned short* __restrict__ WT) {
    int mat = blockIdx.y;
    const float* src = (mat == 0) ? embW
                     : (mat <= L) ? W1 + (size_t)(mat - 1) * H * H
                                  : W2 + (size_t)(mat - 1 - L) * H * H;
    int t = blockIdx.x * 256 + threadIdx.x;   // 0..16383
    int col = t >> 7, k = t & 127;
    WT[(size_t)mat * H * H + col * H + k] = (unsigned short)f2bf(src[(size_t)k * H + col]);
}

// ---------------- CSR build ----------------
__global__ void count_kernel(const int* __restrict__ dst, int E, int* __restrict__ indptr) {
    int e = blockIdx.x * blockDim.x + threadIdx.x;
    if (e < E) atomicAdd(&indptr[1 + dst[e]], 1);
}

__global__ __launch_bounds__(256) void scan1_kernel(const int* __restrict__ P, int N, int NB,
                                                    int* __restrict__ bsum) {
    __shared__ int ls[256];
    int b = blockIdx.x, t = threadIdx.x;
    int chunk = (N + NB - 1) / NB;
    int s0 = b * chunk, s1 = min(s0 + chunk, N);
    int s = 0;
    for (int i = s0 + t; i < s1; i += 256) s += P[i];
    ls[t] = s;
    __syncthreads();
    for (int off = 128; off > 0; off >>= 1) {
        if (t < off) ls[t] += ls[t + off];
        __syncthreads();
    }
    if (t == 0) bsum[b] = ls[0];
}

__global__ void scan2_kernel(int* __restrict__ bsum, int NB) {
    __shared__ int ls[128];
    int t = threadIdx.x;
    int v = (t < NB) ? bsum[t] : 0;
    ls[t] = v;
    __syncthreads();
    for (int off = 1; off < 128; off <<= 1) {
        int u = (t >= off) ? ls[t - off] : 0;
        __syncthreads();
        ls[t] += u;
        __syncthreads();
    }
    if (t < NB) bsum[t] = (t == 0) ? 0 : ls[t - 1];
}

__global__ __launch_bounds__(256) void scan3_kernel(int* __restrict__ P, int* __restrict__ cursor,
                                                    const int* __restrict__ bsum, int N, int NB) {
    __shared__ int ls[256];
    int b = blockIdx.x, t = threadIdx.x;
    int chunk = (N + NB - 1) / NB;
    int sc = (chunk + 255) >> 8;
    int start = b * chunk + t * sc;
    int lim = min((b + 1) * chunk, N);
    int end = min(start + sc, lim);
    int s = 0;
    for (int g = start; g < end; ++g) s += P[g];
    ls[t] = s;
    __syncthreads();
    for (int off = 1; off < 256; off <<= 1) {
        int u = (t >= off) ? ls[t - off] : 0;
        __syncthreads();
        ls[t] += u;
        __syncthreads();
    }
    int run = bsum[b] + ((t == 0) ? 0 : ls[t - 1]);
    for (int g = start; g < end; ++g) {
        int v = P[g];
        cursor[g] = run;
        run += v;
        P[g] = run;
    }
}

__global__ void fill_kernel(const int* __restrict__ src, const int* __restrict__ dst, int E,
                            int* __restrict__ cursor, int* __restrict__ esrc) {
    int e = blockIdx.x * blockDim.x + threadIdx.x;
    if (e < E) {
        int pos = atomicAdd(&cursor[dst[e]], 1);
        esrc[pos] = src[e];
    }
}

// ---------------- neighbor aggregation (bf16 in, bf16 out), 8 independent gather chains ----------------
__global__ __launch_bounds__(256) void agg_kernel(const unsigned short* __restrict__ Hb,
                                                  const int* __restrict__ indptr,
                                                  const int* __restrict__ esrc,
                                                  const float* __restrict__ eps, int layer,
                                                  unsigned short* __restrict__ ZB, int N) {
    int node = blockIdx.x * 4 + (threadIdx.x >> 6);
    int lane = threadIdx.x & 63;
    if (node >= N) return;
    const unsigned int* H2 = (const unsigned int*)Hb;
    float e1 = 1.0f + eps[layer];
    unsigned int hv = H2[(size_t)node * 64 + lane];
    float ax[8], ay[8];
    ax[0] = e1 * bf2f(hv & 0xffffu);
    ay[0] = e1 * bf2f(hv >> 16);
#pragma unroll
    for (int u = 1; u < 8; ++u) { ax[u] = 0.f; ay[u] = 0.f; }
    int jb = indptr[node], je = indptr[node + 1];
    int j = jb;
    for (; j + 7 < je; j += 8) {
        unsigned int v[8];
#pragma unroll
        for (int u = 0; u < 8; ++u) v[u] = H2[(size_t)esrc[j + u] * 64 + lane];
#pragma unroll
        for (int u = 0; u < 8; ++u) {
            ax[u] += bf2f(v[u] & 0xffffu);
            ay[u] += bf2f(v[u] >> 16);
        }
    }
    for (; j + 1 < je; j += 2) {
        unsigned int v0 = H2[(size_t)esrc[j] * 64 + lane];
        unsigned int v1 = H2[(size_t)esrc[j + 1] * 64 + lane];
        ax[0] += bf2f(v0 & 0xffffu); ay[0] += bf2f(v0 >> 16);
        ax[1] += bf2f(v1 & 0xffffu); ay[1] += bf2f(v1 >> 16);
    }
    if (j < je) {
        unsigned int v0 = H2[(size_t)esrc[j] * 64 + lane];
        ax[0] += bf2f(v0 & 0xffffu); ay[0] += bf2f(v0 >> 16);
    }
    float axs = ((ax[0] + ax[1]) + (ax[2] + ax[3])) + ((ax[4] + ax[5]) + (ax[6] + ax[7]));
    float ays = ((ay[0] + ay[1]) + (ay[2] + ay[3])) + ((ay[4] + ay[5]) + (ay[6] + ay[7]));
    ((unsigned int*)ZB)[(size_t)node * 64 + lane] = f2bf(axs) | (f2bf(ays) << 16);
}

// ---------------- MFMA GEMM: out = f(A) @ W + bias ----------------
// Block: 256 thr / 4 waves; 64 rows x 128 cols; wave w owns cols w*32..+31.
// WT is bf16 col-major [col*128 + k]. ABF16: A bf16 (else f32).
// TRANS: f(A)=relu(ca*A+cc), coeffs from sum_in/sq_in.
// STATS: column sum/sumsq of out. POOLF: segment-pool of out. Output is bf16.
template <bool ABF16, bool TRANS, bool STATS, bool POOLF>
__global__ __launch_bounds__(256, 4) void mgemm_kernel(
    const float* __restrict__ Af, const unsigned short* __restrict__ Ab,
    const unsigned short* __restrict__ WT, const float* __restrict__ bias,
    const float* __restrict__ sum_in, const float* __restrict__ sq_in,
    const float* __restrict__ gam, const float* __restrict__ bet, float invN,
    unsigned short* __restrict__ outB,
    int N, float* __restrict__ sum_out, float* __restrict__ sq_out,
    const int* __restrict__ gids, float* __restrict__ pool) {
    __shared__ unsigned short As[64 * 136];   // padded row stride: 272B = 17x16B
    __shared__ float cas[H], ccs[H];
    int tid = threadIdx.x;
    int w = tid >> 6, lane = tid & 63, q = lane >> 4, m = lane & 15;
    int row0 = blockIdx.x * 64;
    int colbase = w * 32;

    // ---- W -> B-fragments: one 16B load per fragment from col-major bf16 WT ----
    short8 bfrag[2][4];
#pragma unroll
    for (int nt = 0; nt < 2; ++nt) {
        const unsigned short* wc = WT + (size_t)(colbase + nt * 16 + m) * H;
#pragma unroll
        for (int kk = 0; kk < 4; ++kk)
            bfrag[nt][kk] = *(const short8*)&wc[kk * 32 + q * 8];
    }

    if (TRANS) {
        if (tid < H) {
            float mu = sum_in[tid] * invN;
            float var = sq_in[tid] * invN - mu * mu;
            float inv = rsqrtf(var + 1e-5f);
            float a = gam[tid] * inv;
            cas[tid] = a;
            ccs[tid] = bet[tid] - mu * a;
        }
        __syncthreads();
    }

    // ---- stage A tile: thread = 4 rows x 8 cols ----
    {
        int cc = tid & 15, rg = tid >> 4;
        int c0 = cc * 8;
        float a8[8], b8[8];
        if (TRANS) {
#pragma unroll
            for (int j = 0; j < 8; ++j) { a8[j] = cas[c0 + j]; b8[j] = ccs[c0 + j]; }
        }
#pragma unroll
        for (int rr = 0; rr < 4; ++rr) {
            int r = rg * 4 + rr;
            int gr = row0 + r;
            uint4 o = {0u, 0u, 0u, 0u};
            if (ABF16 && !TRANS) {
                if (gr < N) o = *(const uint4*)&Ab[(size_t)gr * H + c0];
            } else {
                float v[8] = {0.f, 0.f, 0.f, 0.f, 0.f, 0.f, 0.f, 0.f};
                if (gr < N) {
                    if (ABF16) {
                        uint4 x = *(const uint4*)&Ab[(size_t)gr * H + c0];
                        v[0] = bf2f(x.x & 0xffffu); v[1] = bf2f(x.x >> 16);
                        v[2] = bf2f(x.y & 0xffffu); v[3] = bf2f(x.y >> 16);
                        v[4] = bf2f(x.z & 0xffffu); v[5] = bf2f(x.z >> 16);
                        v[6] = bf2f(x.w & 0xffffu); v[7] = bf2f(x.w >> 16);
                    } else {
                        float4 x0 = *(const float4*)&Af[(size_t)gr * H + c0];
                        float4 x1 = *(const float4*)&Af[(size_t)gr * H + c0 + 4];
                        v[0] = x0.x; v[1] = x0.y; v[2] = x0.z; v[3] = x0.w;
                        v[4] = x1.x; v[5] = x1.y; v[6] = x1.z; v[7] = x1.w;
                    }
                }
                if (TRANS) {
#pragma unroll
                    for (int j = 0; j < 8; ++j) v[j] = fmaxf(a8[j] * v[j] + b8[j], 0.f);
                }
                o.x = f2bf(v[0]) | (f2bf(v[1]) << 16);
                o.y = f2bf(v[2]) | (f2bf(v[3]) << 16);
                o.z = f2bf(v[4]) | (f2bf(v[5]) << 16);
                o.w = f2bf(v[6]) | (f2bf(v[7]) << 16);
            }
            *(uint4*)&As[r * 136 + c0] = o;
        }
    }
    __syncthreads();

    // ---- MFMA main: 4 m-tiles x 2 n-tiles x 4 k-steps ----
    f32x4 acc[4][2];
#pragma unroll
    for (int mt = 0; mt < 4; ++mt)
#pragma unroll
        for (int nt = 0; nt < 2; ++nt) acc[mt][nt] = (f32x4){0.f, 0.f, 0.f, 0.f};

#pragma unroll
    for (int kk = 0; kk < 4; ++kk) {
        short8 af[4];
#pragma unroll
        for (int mt = 0; mt < 4; ++mt)
            af[mt] = *(const short8*)&As[(mt * 16 + m) * 136 + kk * 32 + q * 8];
#pragma unroll
        for (int mt = 0; mt < 4; ++mt)
#pragma unroll
            for (int nt = 0; nt < 2; ++nt)
                acc[mt][nt] = __builtin_amdgcn_mfma_f32_16x16x32_bf16(
                    af[mt], bfrag[nt][kk], acc[mt][nt], 0, 0, 0);
    }

    // ---- epilogue: bias, stores, stats, pool ----
    float bs2[2] = {bias[colbase + m], bias[colbase + 16 + m]};
    float s[2] = {0.f, 0.f}, qq[2] = {0.f, 0.f};
#pragma unroll
    for (int mt = 0; mt < 4; ++mt) {
#pragma unroll
        for (int nt = 0; nt < 2; ++nt) {
            int gcol = colbase + nt * 16 + m;
#pragma unroll
            for (int rg = 0; rg < 4; ++rg) {
                int grow = row0 + mt * 16 + q * 4 + rg;
                float v = acc[mt][nt][rg] + bs2[nt];
                if (grow < N) {
                    outB[(size_t)grow * H + gcol] = (unsigned short)f2bf(v);
                    if (STATS || POOLF) {
                        s[nt] += v;
                        if (STATS) qq[nt] += v * v;
                    }
                }
            }
        }
    }

    if (STATS) {
#pragma unroll
        for (int nt = 0; nt < 2; ++nt) {
            float sv = s[nt], qv = qq[nt];
            sv += __shfl_xor(sv, 16); sv += __shfl_xor(sv, 32);
            qv += __shfl_xor(qv, 16); qv += __shfl_xor(qv, 32);
            if (q == 0) {
                atomicAdd(&sum_out[colbase + nt * 16 + m], sv);
                atomicAdd(&sq_out[colbase + nt * 16 + m], qv);
            }
        }
    }

    if (POOLF) {
        int last = min(row0 + 63, N - 1);
        bool uni = (gids[row0] == gids[last]);
        if (uni) {
            int g = gids[row0];
#pragma unroll
            for (int nt = 0; nt < 2; ++nt) {
                float sv = s[nt];
                sv += __shfl_xor(sv, 16); sv += __shfl_xor(sv, 32);
                if (q == 0) atomicAdd(&pool[g * H + colbase + nt * 16 + m], sv);
            }
        } else {
#pragma unroll
            for (int mt = 0; mt < 4; ++mt)
#pragma unroll
                for (int nt = 0; nt < 2; ++nt)
#pragma unroll
                    for (int rg = 0; rg < 4; ++rg) {
                        int grow = row0 + mt * 16 + q * 4 + rg;
                        if (grow < N) {
                            float v = acc[mt][nt][rg] + bs2[nt];
                            atomicAdd(&pool[gids[grow] * H + colbase + nt * 16 + m], v);
                        }
                    }
        }
    }
}

// ---------------- stats of v = relu(ca*U+cc)*snorm, coeffs computed inline ----------------
__global__ __launch_bounds__(256) void statsv_kernel(const unsigned short* __restrict__ UB,
                                                     const float* __restrict__ snorm,
                                                     const float* __restrict__ sum2, const float* __restrict__ sq2,
                                                     const float* __restrict__ ga, const float* __restrict__ ba,
                                                     float invN, int N,
                                                     float* __restrict__ sum3, float* __restrict__ sq3) {
    __shared__ float cas[H], ccs[H];
    int t = threadIdx.x;
    if (t < H) {
        float m = sum2[t] * invN;
        float var = sq2[t] * invN - m * m;
        float inv = rsqrtf(var + 1e-5f);
        float a = ga[t] * inv;
        cas[t] = a;
        ccs[t] = ba[t] - m * a;
    }
    __syncthreads();
    int col2 = t & 63, part = t >> 6;
    int c0 = col2 * 2, c1 = c0 + 1;
    float a0 = cas[c0], b0 = ccs[c0], a1 = cas[c1], b1 = ccs[c1];
    float s0 = 0.f, q0 = 0.f, s1 = 0.f, q1 = 0.f;
    const unsigned int* U2 = (const unsigned int*)UB;
    for (int r = blockIdx.x * 4 + part; r < N; r += gridDim.x * 4) {
        float sn = snorm[r];
        unsigned int v = U2[(size_t)r * 64 + col2];
        float v0 = fmaxf(a0 * bf2f(v & 0xffffu) + b0, 0.f) * sn;
        float v1 = fmaxf(a1 * bf2f(v >> 16) + b1, 0.f) * sn;
        s0 += v0; q0 += v0 * v0;
        s1 += v1; q1 += v1 * v1;
    }
    __shared__ float S[4][H], Q[4][H];
    S[part][c0] = s0; S[part][c1] = s1;
    Q[part][c0] = q0; Q[part][c1] = q1;
    __syncthreads();
    if (t < H) {
        atomicAdd(&sum3[t], S[0][t] + S[1][t] + S[2][t] + S[3][t]);
        atomicAdd(&sq3[t], Q[0][t] + Q[1][t] + Q[2][t] + Q[3][t]);
    }
}

// ---------------- residual tail (bf16 residual) + fused pooling ----------------
__global__ __launch_bounds__(256) void tail_kernel(unsigned short* __restrict__ Hb,
                                                   const unsigned short* __restrict__ UB,
                                                   const float* __restrict__ snorm,
                                                   const float* __restrict__ sum2, const float* __restrict__ sq2,
                                                   const float* __restrict__ ga, const float* __restrict__ ba,
                                                   const float* __restrict__ sum3, const float* __restrict__ sq3,
                                                   const float* __restrict__ gl, const float* __restrict__ bl,
                                                   float invN, const int* __restrict__ gids,
                                                   float* __restrict__ pool, int N) {
    __shared__ float ca2[H], cc2[H], ca3[H], cc3[H];
    __shared__ float PS[8][H];
    int t = threadIdx.x;
    if (t < H) {
        float m2 = sum2[t] * invN, v2 = sq2[t] * invN - m2 * m2;
        float i2 = rsqrtf(v2 + 1e-5f), a2 = ga[t] * i2;
        ca2[t] = a2; cc2[t] = ba[t] - m2 * a2;
        float m3 = sum3[t] * invN, v3 = sq3[t] * invN - m3 * m3;
        float i3 = rsqrtf(v3 + 1e-5f), a3 = gl[t] * i3;
        ca3[t] = a3; cc3[t] = bl[t] - m3 * a3;
    }
    __syncthreads();
    int row0 = blockIdx.x * 32;
    int col4 = t & 31, rowg = t >> 5;
    int c0 = col4 * 4;
    float A2[4], B2[4], A3[4], B3[4];
#pragma unroll
    for (int j = 0; j < 4; ++j) {
        A2[j] = ca2[c0 + j]; B2[j] = cc2[c0 + j];
        A3[j] = ca3[c0 + j]; B3[j] = cc3[c0 + j];
    }
    bool uni = (gids[row0] == gids[min(row0 + 31, N - 1)]);
    float p[4] = {0.f, 0.f, 0.f, 0.f};
    const uint2* U4 = (const uint2*)UB;
    uint2* H4 = (uint2*)Hb;
#pragma unroll
    for (int rr = 0; rr < 4; ++rr) {
        int r = row0 + rowg * 4 + rr;
        if (r < N) {
            float sn = snorm[r];
            uint2 uv = U4[(size_t)r * 32 + col4];
            uint2 hv = H4[(size_t)r * 32 + col4];
            float u[4] = {bf2f(uv.x & 0xffffu), bf2f(uv.x >> 16), bf2f(uv.y & 0xffffu), bf2f(uv.y >> 16)};
            float h[4] = {bf2f(hv.x & 0xffffu), bf2f(hv.x >> 16), bf2f(hv.y & 0xffffu), bf2f(hv.y >> 16)};
#pragma unroll
            for (int j = 0; j < 4; ++j) {
                float v = fmaxf(A2[j] * u[j] + B2[j], 0.f) * sn;
                h[j] += fmaxf(A3[j] * v + B3[j], 0.f);
            }
            uint2 hb;
            hb.x = f2bf(h[0]) | (f2bf(h[1]) << 16);
            hb.y = f2bf(h[2]) | (f2bf(h[3]) << 16);
            H4[(size_t)r * 32 + col4] = hb;
            if (uni) {
                p[0] += h[0]; p[1] += h[1]; p[2] += h[2]; p[3] += h[3];
            } else {
                int g = gids[r];
#pragma unroll
                for (int j = 0; j < 4; ++j) atomicAdd(&pool[g * H + c0 + j], h[j]);
            }
        }
    }
    if (uni) {
#pragma unroll
        for (int j = 0; j < 4; ++j) PS[rowg][c0 + j] = p[j];
        __syncthreads();
        if (t < H) {
            float s = PS[0][t] + PS[1][t] + PS[2][t] + PS[3][t] +
                      PS[4][t] + PS[5][t] + PS[6][t] + PS[7][t];
            atomicAdd(&pool[gids[row0] * H + t], s);
        }
    }
}

// ---------------- final: score = sum_i pooled_i @ predW_i + predb_i ----------------
__global__ void final_kernel(const float* __restrict__ pool, const float* __restrict__ pw,
                             const float* __restrict__ pb, float* __restrict__ out) {
    int g = blockIdx.x, t = threadIdx.x;
    __shared__ float p[H];
    float acc = 0.f;
    for (int i = 0; i <= L; ++i) {
        p[t] = pool[(size_t)(i * G + g) * H + t];
        __syncthreads();
        if (t < C) {
            float s = 0.f;
            for (int f = 0; f < H; ++f) s += p[f] * pw[(size_t)(i * H + f) * C + t];
            acc += s + pb[i * C + t];
        }
        __syncthreads();
    }
    if (t < C) out[g * C + t] = acc;
}

extern "C" void kernel_launch(void* const* d_in, const int* in_sizes, int n_in,
                              void* d_out, int out_size, void* d_ws, size_t ws_size,
                              hipStream_t stream) {
    const float* h_in  = (const float*)d_in[0];
    const float* snorm = (const float*)d_in[1];
    const int* esrc_in = (const int*)d_in[2];
    const int* edst_in = (const int*)d_in[3];
    const int* gids    = (const int*)d_in[4];
    const float* embW = (const float*)d_in[5];
    const float* embB = (const float*)d_in[6];
    const float* eps  = (const float*)d_in[7];
    const float* W1   = (const float*)d_in[8];
    const float* b1   = (const float*)d_in[9];
    const float* g1   = (const float*)d_in[10];
    const float* be1  = (const float*)d_in[11];
    const float* W2   = (const float*)d_in[12];
    const float* b2   = (const float*)d_in[13];
    const float* ga   = (const float*)d_in[14];
    const float* ba   = (const float*)d_in[15];
    const float* gl   = (const float*)d_in[16];
    const float* bl   = (const float*)d_in[17];
    const float* predW = (const float*)d_in[18];
    const float* predB = (const float*)d_in[19];

    const int N = in_sizes[0] / H;  // 50000
    const int E = in_sizes[2];      // 600000
    const float invN = 1.0f / (float)N;

    // ws layout (all sections 16B-aligned by construction)
    float* ws = (float*)d_ws;
    float* POOL = ws;                                        // (L+1)*G*H
    float* STATS = POOL + (size_t)(L + 1) * G * H;           // L*6*H
    unsigned short* WT = (unsigned short*)(STATS + (size_t)L * 6 * H);  // 9*H*H bf16
    int* INDPTR = (int*)(WT + (size_t)9 * H * H);            // N+1 (pad to N+4)
    int* CURSOR = INDPTR + (N + 4);                          // N
    int* BSUM   = CURSOR + N;                                // SCAN_NB
    int* ESRC   = BSUM + SCAN_NB;                            // E
    unsigned short* Hb = (unsigned short*)(ESRC + E);        // N*H bf16 (residual)
    unsigned short* ZB = Hb + (size_t)N * H;                 // N*H bf16
    unsigned short* TB = ZB + (size_t)N * H;                 // N*H bf16
    unsigned short* UB = ZB;                                 // alias: Z dead when U written

    size_t zbytes = ((size_t)(L + 1) * G * H + (size_t)L * 6 * H) * 4
                  + (size_t)9 * H * H * 2 + (size_t)(N + 4) * 4;
    hipMemsetAsync(POOL, 0, zbytes, stream);

    wprep_kernel<<<dim3(64, 9), 256, 0, stream>>>(embW, W1, W2, WT);
    count_kernel<<<(E + 255) / 256, 256, 0, stream>>>(edst_in, E, INDPTR);
    scan1_kernel<<<SCAN_NB, 256, 0, stream>>>(INDPTR + 1, N, SCAN_NB, BSUM);
    scan2_kernel<<<1, 128, 0, stream>>>(BSUM, SCAN_NB);
    scan3_kernel<<<SCAN_NB, 256, 0, stream>>>(INDPTR + 1, CURSOR, BSUM, N, SCAN_NB);
    fill_kernel<<<(E + 255) / 256, 256, 0, stream>>>(esrc_in, edst_in, E, CURSOR, ESRC);

    int gblocks = (N + 63) / 64;
    // embedding: A=f32 h_in -> Hb bf16, fused pool into POOL[0]
    mgemm_kernel<false, false, false, true><<<gblocks, 256, 0, stream>>>(
        h_in, nullptr, WT, embB, nullptr, nullptr, nullptr, nullptr, invN,
        Hb, N, nullptr, nullptr, gids, POOL);

    for (int i = 0; i < L; ++i) {
        float* S1 = STATS + (size_t)i * 6 * H;
        float* Q1 = S1 + H;
        float* S2 = Q1 + H;
        float* Q2 = S2 + H;
        float* S3 = Q2 + H;
        float* Q3 = S3 + H;
        agg_kernel<<<(N + 3) / 4, 256, 0, stream>>>(Hb, INDPTR, ESRC, eps, i, ZB, N);
        // gemm1: A=ZB bf16 -> TB bf16, stats S1/Q1
        mgemm_kernel<true, false, true, false><<<gblocks, 256, 0, stream>>>(
            nullptr, ZB, WT + (size_t)(1 + i) * H * H, b1 + (size_t)i * H,
            nullptr, nullptr, nullptr, nullptr, invN,
            TB, N, S1, Q1, nullptr, nullptr);
        // gemm2: A=TB bf16 with BN1-affine+relu -> UB bf16, stats S2/Q2
        mgemm_kernel<true, true, true, false><<<gblocks, 256, 0, stream>>>(
            nullptr, TB, WT + (size_t)(1 + L + i) * H * H, b2 + (size_t)i * H,
            S1, Q1, g1 + (size_t)i * H, be1 + (size_t)i * H, invN,
            UB, N, S2, Q2, nullptr, nullptr);
        statsv_kernel<<<256, 256, 0, stream>>>(UB, snorm, S2, Q2,
                                               ga + (size_t)i * H, ba + (size_t)i * H, invN, N, S3, Q3);
        tail_kernel<<<(N + 31) / 32, 256, 0, stream>>>(Hb, UB, snorm,
                                                       S2, Q2, ga + (size_t)i * H, ba + (size_t)i * H,
                                                       S3, Q3, gl + (size_t)i * H, bl + (size_t)i * H,
                                                       invN, gids, POOL + (size_t)(i + 1) * G * H, N);
    }
    final_kernel<<<G, H, 0, stream>>>(POOL, predW, predB, (float*)d_out);
}